// Round 7
// baseline (266.484 us; speedup 1.0000x reference)
//
#include <hip/hip_runtime.h>
#include <hip/hip_bf16.h>
#include <stdint.h>

#define BATCH 4
#define NPTS  4096
#define DIM   128
#define KNN   16
#define NROWS (BATCH*NPTS)   // 16384
#define NCHUNK 16
#define CHUNK  (NPTS/NCHUNK) // 256

typedef unsigned long long u64;
typedef unsigned int u32;
typedef unsigned short u16;
typedef __attribute__((ext_vector_type(8))) short short8;
typedef __attribute__((ext_vector_type(4))) float f32x4;

__device__ __forceinline__ u16 f2bf(float f) {
  u32 u = __float_as_uint(f);
  u += 0x7FFFu + ((u >> 16) & 1);   // RNE
  return (u16)(u >> 16);
}

// wave-internal LDS fence: a wave's DS ops issue in program order; waiting on
// lgkmcnt(0) makes cross-LANE (same wave) LDS data visible. Compiler reorder
// blocked by the memory clobber.
#define WAVE_LDS_FENCE() asm volatile("s_waitcnt lgkmcnt(0)" ::: "memory")

// ---------------- prep: pad pos (B,N,3) -> float4 ----------------
__global__ __launch_bounds__(256) void prep_pos4(const float* __restrict__ pos,
                                                 float4* __restrict__ pos4) {
  int i = blockIdx.x * 256 + threadIdx.x;
  if (i < NROWS) pos4[i] = make_float4(pos[3*i], pos[3*i+1], pos[3*i+2], 0.f);
}

// ---------------- prep: folded weight products ----------------
__global__ __launch_bounds__(256) void prep_matmul(
    const float* __restrict__ pw2, const float* __restrict__ qw, const float* __restrict__ kw,
    const float* __restrict__ aw1,
    u16* __restrict__ w1T, float* __restrict__ Wq2, float* __restrict__ Wk2) {
  int p = blockIdx.x >> 2, qtr = blockIdx.x & 3;
  const float* A = p == 0 ? pw2 : (p == 1 ? qw : kw);
  int j = threadIdx.x & 31;
  int r0 = qtr*32 + (threadIdx.x >> 5)*4;
  float acc[4] = {0.f,0.f,0.f,0.f};
  for (int c = 0; c < 128; ++c) {
    float av = aw1[c*32 + j];
#pragma unroll
    for (int rr = 0; rr < 4; ++rr) acc[rr] = fmaf(A[(r0+rr)*128 + c], av, acc[rr]);
  }
#pragma unroll
  for (int rr = 0; rr < 4; ++rr) {
    int h = r0 + rr;
    if (p == 0)      w1T[j*128 + (h ^ ((j&7)<<3))] = f2bf(acc[rr]);
    else if (p == 1) Wq2[h*32 + j] = acc[rr];
    else             Wk2[h*32 + j] = acc[rr];
  }
}

// ---------------- prep: bf16 transposed/swizzled weights + pw1 float4 + bias1 ----------------
__global__ __launch_bounds__(256) void prep_convert(
    const float* __restrict__ pw2, const float* __restrict__ aw2,
    const float* __restrict__ pw1, const float* __restrict__ pb1,
    const float* __restrict__ qb, const float* __restrict__ kb,
    const float* __restrict__ pb2, const float* __restrict__ aw1, const float* __restrict__ ab1,
    u16* __restrict__ pw2T, u16* __restrict__ aw2T,
    float4* __restrict__ pw1q, float* __restrict__ bias1) {
  int bid = blockIdx.x, tid = threadIdx.x;
  if (bid < 64) {
    int e = bid*256 + tid; int k = e >> 7, n = e & 127;
    pw2T[n*128 + (k ^ ((n&7)<<3))] = f2bf(pw2[k*128 + n]);
  } else if (bid < 80) {
    int e = (bid-64)*256 + tid; int k = e >> 7, n = e & 127;
    aw2T[n*32 + (k ^ ((n&3)<<3))] = f2bf(aw2[k*128 + n]);
  } else {
    if (tid < 128) {
      int c = tid;
      pw1q[c ^ ((c & 0x18) >> 2)] = make_float4(pw1[c], pw1[128+c], pw1[256+c], pb1[c]);
    } else if (tid < 160) {
      int j = tid - 128;
      float s = ab1[j];
      for (int c = 0; c < 128; ++c) s += (qb[c]-kb[c]+pb2[c]) * aw1[c*32+j];
      bias1[j] = s;
    }
  }
}

// ---------------- branchless sorting primitives ----------------
template <typename T>
__device__ __forceinline__ void cex(T& a, T& b) {
  T mn = a < b ? a : b;
  T mx = a < b ? b : a;
  a = mn; b = mx;
}
template <typename T>
__device__ __forceinline__ void sort16(T x[16]) {
#pragma unroll
  for (int k = 2; k <= 16; k <<= 1)
#pragma unroll
    for (int j = k >> 1; j > 0; j >>= 1)
#pragma unroll
      for (int i = 0; i < 16; ++i) {
        int l = i ^ j;
        if (l > i) { if ((i & k) == 0) cex(x[i], x[l]); else cex(x[l], x[i]); }
      }
}
template <typename T>
__device__ __forceinline__ void merge16(T A[16], const T B[16]) {
#pragma unroll
  for (int i = 0; i < 16; ++i) { T b = B[15 - i]; A[i] = A[i] < b ? A[i] : b; }
#pragma unroll
  for (int j = 8; j > 0; j >>= 1)
#pragma unroll
    for (int i = 0; i < 16; ++i) { int l = i ^ j; if (l > i) cex(A[i], A[l]); }
}
// sorts a bitonic 32-sequence ascending
__device__ __forceinline__ void bmerge32(u32 x[32]) {
#pragma unroll
  for (int j = 16; j > 0; j >>= 1)
#pragma unroll
    for (int i = 0; i < 32; ++i) { int l = i ^ j; if (l > i) cex(x[i], x[l]); }
}

// ---------------- kNN pass 1: fp32 keys with GLOBAL 12-bit idx; transposed output ----------------
__global__ __launch_bounds__(256) void knn_scan(const float4* __restrict__ pos4,
                                                u32* __restrict__ part) {
  __shared__ float4 cs[4][CHUNK];   // 16 KB
  const int lane  = threadIdx.x & 63;
  const int w     = threadIdx.x >> 6;
  const int task  = blockIdx.x * 4 + w;     // 0..4095
  const int qg    = task >> 4;              // 0..255
  const int chunk = task & 15;              // 0..15
  const int qbase = qg * 64;
  const int b     = qbase >> 12;
  const int cbase = chunk * CHUNK;

  const float4* cand = pos4 + b*NPTS + cbase;
#pragma unroll
  for (int i = 0; i < CHUNK/64; ++i) cs[w][lane + 64*i] = cand[lane + 64*i];
  __syncthreads();

  float4 qp = pos4[qbase + lane];
  const float qx = qp.x, qy = qp.y, qz = qp.z;

  u32 best[16];
#pragma unroll
  for (int i = 0; i < 16; ++i) best[i] = ~0u;

#pragma unroll 1
  for (int m = 0; m < CHUNK/16; ++m) {
    u32 batch[16];
#pragma unroll
    for (int e = 0; e < 16; ++e) {
      float4 p = cs[w][m*16 + e];
      float dx = qx - p.x, dy = qy - p.y, dz = qz - p.z;
      float d  = fmaf(dx, dx, fmaf(dy, dy, dz*dz));
      batch[e] = (__float_as_uint(d) & 0xFFFFF000u) | (u32)(cbase + m*16 + e);
    }
    sort16(batch);
    merge16(best, batch);
  }
  const int q = qbase + lane;
  uint4* dst = (uint4*)(part + q*256 + chunk*16);
#pragma unroll
  for (int t = 0; t < 4; ++t)
    dst[t] = make_uint4(best[4*t], best[4*t+1], best[4*t+2], best[4*t+3]);
}

// ---------------- kNN pass 2: u32 keep-32 merge tree + fp64 re-rank of pool ----------------
__global__ __launch_bounds__(256) void knn_refine(const float4* __restrict__ pos4,
                                                  const u32* __restrict__ part,
                                                  int* __restrict__ knnIdx) {
  __shared__ u64 A64[16][137];        // aliased as u32[16][274] for the tree
  __shared__ u32 Bu[16][264];
  u32 (*Au)[274] = (u32 (*)[274])A64;

  const int tid = threadIdx.x;
  const int qi = tid >> 4, c = tid & 15;
  const int q  = blockIdx.x * 16 + qi;
  const int b  = q >> 12;

  {
    const uint4* src = (const uint4*)(part + q*256 + c*16);
    u32 own[16];
#pragma unroll
    for (int t = 0; t < 4; ++t) {
      uint4 v = src[t];
      own[4*t+0]=v.x; own[4*t+1]=v.y; own[4*t+2]=v.z; own[4*t+3]=v.w;
    }
#pragma unroll
    for (int s = 0; s < 16; ++s) Au[qi][c*17 + s] = own[s];
  }
  __syncthreads();

  if (c < 8) {
    u32 x[32];
#pragma unroll
    for (int s = 0; s < 16; ++s) x[s]      = Au[qi][(2*c)*17 + s];
#pragma unroll
    for (int s = 0; s < 16; ++s) x[16 + s] = Au[qi][(2*c+1)*17 + 15 - s];
    bmerge32(x);
#pragma unroll
    for (int s = 0; s < 32; ++s) Bu[qi][c*33 + s] = x[s];
  }
  __syncthreads();

  if (c < 4) {
    u32 x[32];
#pragma unroll
    for (int s = 0; s < 32; ++s) {
      u32 a = Bu[qi][(2*c)*33 + s], bb = Bu[qi][(2*c+1)*33 + 31 - s];
      x[s] = a < bb ? a : bb;
    }
    bmerge32(x);
#pragma unroll
    for (int s = 0; s < 32; ++s) Au[qi][c*33 + s] = x[s];
  }
  __syncthreads();

  if (c < 2) {
    u32 x[32];
#pragma unroll
    for (int s = 0; s < 32; ++s) {
      u32 a = Au[qi][(2*c)*33 + s], bb = Au[qi][(2*c+1)*33 + 31 - s];
      x[s] = a < bb ? a : bb;
    }
    bmerge32(x);
#pragma unroll
    for (int s = 0; s < 32; ++s) Bu[qi][c*33 + s] = x[s];
  }
  __syncthreads();

  if (c == 0) {
    u32 x[32];
#pragma unroll
    for (int s = 0; s < 32; ++s) {
      u32 a = Bu[qi][s], bb = Bu[qi][33 + 31 - s];
      x[s] = a < bb ? a : bb;
    }
    bmerge32(x);
#pragma unroll
    for (int s = 0; s < 32; ++s) Bu[qi][132 + s] = x[s];
  }
  __syncthreads();

  if (c < 2) {
    float4 qp = pos4[q];
    const double qx = qp.x, qy = qp.y, qz = qp.z;
    u64 key[16];
#pragma unroll
    for (int s = 0; s < 16; ++s) {
      int idx = (int)(Bu[qi][132 + c*16 + s] & 0xFFFu);
      float4 p = pos4[(b<<12) + idx];
      double dx = qx - (double)p.x;
      double dy = qy - (double)p.y;
      double dz = qz - (double)p.z;
      double d  = fma(dx, dx, fma(dy, dy, dz*dz));
      key[s] = (((u64)__double_as_longlong(d)) & ~0xFFFull) | (u64)idx;
    }
    sort16(key);
#pragma unroll
    for (int s = 0; s < 16; ++s) A64[qi][c*17 + s] = key[s];
  }
  __syncthreads();

  if (c == 0) {
    u64 best[16], nb[16];
#pragma unroll
    for (int s = 0; s < 16; ++s) { best[s] = A64[qi][s]; nb[s] = A64[qi][17 + s]; }
    merge16(best, nb);
    const int outq = q * KNN;
#pragma unroll
    for (int s = 0; s < 16; ++s) knnIdx[outq + s] = (int)(best[s] & 0xFFFull);
  }
}

// ---------------- proj: V + qa + ka ----------------
__global__ __launch_bounds__(256) void proj_v(
    const float* __restrict__ x,
    const float* __restrict__ vw, const float* __restrict__ vb,
    const float* __restrict__ Wq2, const float* __restrict__ Wk2,
    float* __restrict__ vo, float* __restrict__ qa, float* __restrict__ ka) {
  __shared__ float xs[32*DIM];
  const int row0 = blockIdx.x * 32;
  const int tid = threadIdx.x;
  {
    const float4* src = (const float4*)(x + row0*DIM);
    float4* dst = (float4*)xs;
#pragma unroll
    for (int i = 0; i < 4; ++i) dst[tid + 256*i] = src[tid + 256*i];
  }
  __syncthreads();
  { // V
    const int c = tid & 127, g2 = tid >> 7;
    float av[16];
#pragma unroll
    for (int r = 0; r < 16; ++r) av[r] = 0.f;
    for (int d4 = 0; d4 < 32; ++d4) {
      float wv[4];
#pragma unroll
      for (int t = 0; t < 4; ++t) wv[t] = vw[(d4*4+t)*DIM + c];
#pragma unroll
      for (int r = 0; r < 16; ++r) {
        float4 xv = *(const float4*)&xs[(g2*16+r)*DIM + d4*4];
        av[r] = fmaf(xv.x, wv[0], av[r]);
        av[r] = fmaf(xv.y, wv[1], av[r]);
        av[r] = fmaf(xv.z, wv[2], av[r]);
        av[r] = fmaf(xv.w, wv[3], av[r]);
      }
    }
    float bv = vb[c];
#pragma unroll
    for (int r = 0; r < 16; ++r) vo[(row0 + g2*16 + r)*DIM + c] = av[r] + bv;
  }
  { // qa/ka (32 cols)
    const int j = tid & 31, grp = tid >> 5;
    float aq[4] = {0.f,0.f,0.f,0.f}, ak[4] = {0.f,0.f,0.f,0.f};
    for (int d4 = 0; d4 < 32; ++d4) {
#pragma unroll
      for (int t = 0; t < 4; ++t) {
        int d = d4*4 + t;
        float wq = Wq2[d*32 + j], wk = Wk2[d*32 + j];
#pragma unroll
        for (int rr = 0; rr < 4; ++rr) {
          float xv = xs[(grp*4+rr)*DIM + d];
          aq[rr] = fmaf(xv, wq, aq[rr]);
          ak[rr] = fmaf(xv, wk, ak[rr]);
        }
      }
    }
#pragma unroll
    for (int rr = 0; rr < 4; ++rr) {
      qa[(row0 + grp*4 + rr)*32 + j] = aq[rr];
      ka[(row0 + grp*4 + rr)*32 + j] = ak[rr];
    }
  }
}

// ---------------- fused MFMA attention: 16 waves/block, barrier-free loop ----------------
#define AW 16
__global__ __launch_bounds__(1024, 4) void attn_mfma(
    const float4* __restrict__ pos4, const int* __restrict__ knnIdx,
    const float* __restrict__ vws, const float* __restrict__ qa, const float* __restrict__ ka,
    const u16* __restrict__ pw2T, const u16* __restrict__ w1T, const u16* __restrict__ aw2T,
    const float4* __restrict__ pw1q, const float* __restrict__ bias1,
    const float* __restrict__ pb2, const float* __restrict__ ab2,
    float* __restrict__ out) {
  __shared__ __align__(16) u16 pw2s[16384];   // 32 KB (shared by 16 waves)
  __shared__ __align__(16) u16 w1s[4096];     // 8 KB
  __shared__ __align__(16) u16 aw2s[4096];    // 8 KB
  __shared__ __align__(16) float4 pw1s[128];  // 2 KB
  __shared__ float bias1s[32];
  __shared__ float pb2s[128];
  __shared__ float ab2s[128];
  __shared__ __align__(16) u16 h2t[AW][512];  // per-wave
  __shared__ float4 rels[AW][16];             // per-wave
  __shared__ int ids[AW][16];                 // per-wave

  const int tid = threadIdx.x;
  { // stage weights with all 1024 threads (sources pre-transposed+swizzled)
    const uint4* s1 = (const uint4*)pw2T; uint4* d1 = (uint4*)pw2s;
    d1[tid] = s1[tid];
    d1[tid + 1024] = s1[tid + 1024];
    if (tid < 512)       ((uint4*)w1s)[tid]        = ((const uint4*)w1T)[tid];
    else if (tid < 1024) ((uint4*)aw2s)[tid - 512] = ((const uint4*)aw2T)[tid - 512];
    if (tid < 128) { pw1s[tid] = pw1q[tid]; pb2s[tid] = pb2[tid]; ab2s[tid] = ab2[tid]; }
    else if (tid < 160) bias1s[tid-128] = bias1[tid-128];
  }
  __syncthreads();   // ONLY block barrier; loop below is wave-independent

  const int lane = tid & 63, w = tid >> 6;
  const int c16 = lane & 15, g = lane >> 4;
  // XCD-aware bijective swizzle: 256 blocks, 8 XCDs -> XCD x owns queries [x*2048, x*2048+2048)
  const int swz = (blockIdx.x & 7) * 32 + (blockIdx.x >> 3);
  const int qbase = swz * 64 + w * 4;

  for (int it = 0; it < 4; ++it) {
    const int q = qbase + it;
    const int b = q >> 12;
    if (lane < 16) {
      int id = knnIdx[q*KNN + lane];
      ids[w][lane] = id;
      float4 pq = pos4[q], pn = pos4[(b<<12) + id];
      rels[w][lane] = make_float4(pq.x-pn.x, pq.y-pn.y, pq.z-pn.z, 0.f);
    }
    WAVE_LDS_FENCE();   // cross-lane (same wave) visibility of ids/rels

    int idr[4];
#pragma unroll
    for (int r = 0; r < 4; ++r) idr[r] = ids[w][g*4 + r];

    // early gathers (hide latency under h1/pe/ha)
    float qa_v[2], ka_v[2][4];
#pragma unroll
    for (int t = 0; t < 2; ++t) qa_v[t] = qa[q*32 + t*16 + c16];
#pragma unroll
    for (int r = 0; r < 4; ++r)
#pragma unroll
      for (int t = 0; t < 2; ++t) ka_v[t][r] = ka[((b<<12)+idr[r])*32 + t*16 + c16];

    // h1 in A-fragment layout: lane holds row=c16, k = kc*32 + g*8 + j
    float4 rl = rels[w][c16];
    short8 h1f[4];
#pragma unroll
    for (int kc = 0; kc < 4; ++kc) {
      short8 s;
#pragma unroll
      for (int j = 0; j < 8; ++j) {
        int c = kc*32 + g*8 + j;
        float4 wv = pw1s[c ^ ((c & 0x18) >> 2)];
        float h = fmaf(rl.x, wv.x, fmaf(rl.y, wv.y, fmaf(rl.z, wv.z, wv.w)));
        s[j] = (short)f2bf(fmaxf(h, 0.f));
      }
      h1f[kc] = s;
    }

    // pe = h1 @ pw2
    f32x4 pe[8];
#pragma unroll
    for (int nt = 0; nt < 8; ++nt) { f32x4 z = {0.f,0.f,0.f,0.f}; pe[nt] = z; }
#pragma unroll
    for (int kc = 0; kc < 4; ++kc)
#pragma unroll
      for (int nt = 0; nt < 8; ++nt) {
        int n = nt*16 + c16;
        short8 bf = *(const short8*)&pw2s[n*128 + ((kc*32 + g*8) ^ ((n&7)<<3))];
        pe[nt] = __builtin_amdgcn_mfma_f32_16x16x32_bf16(h1f[kc], bf, pe[nt], 0, 0, 0);
      }

    // ha = h1 @ W1
    f32x4 ha[2];
#pragma unroll
    for (int t = 0; t < 2; ++t) { f32x4 z = {0.f,0.f,0.f,0.f}; ha[t] = z; }
#pragma unroll
    for (int kc = 0; kc < 4; ++kc)
#pragma unroll
      for (int t = 0; t < 2; ++t) {
        int n = t*16 + c16;
        short8 bf = *(const short8*)&w1s[n*128 + ((kc*32 + g*8) ^ ((n&7)<<3))];
        ha[t] = __builtin_amdgcn_mfma_f32_16x16x32_bf16(h1f[kc], bf, ha[t], 0, 0, 0);
      }

    // h2 = relu(ha + qa - ka + bias1) -> bf16 -> per-wave LDS
#pragma unroll
    for (int t = 0; t < 2; ++t)
#pragma unroll
      for (int r = 0; r < 4; ++r) {
        float v = ha[t][r] + qa_v[t] - ka_v[t][r] + bias1s[t*16 + c16];
        int row = g*4 + r, col = t*16 + c16;
        h2t[w][row*32 + (col ^ ((row&3)<<3))] = f2bf(fmaxf(v, 0.f));
      }
    WAVE_LDS_FENCE();   // cross-lane visibility of h2t

    short8 h2f = *(const short8*)&h2t[w][c16*32 + ((g*8) ^ ((c16&3)<<3))];

    // logits = h2 @ aw2 + ab2
    f32x4 lg[8];
#pragma unroll
    for (int nt = 0; nt < 8; ++nt) {
      int n = nt*16 + c16;
      float ab = ab2s[n];
      f32x4 cini = {ab, ab, ab, ab};
      short8 bf = *(const short8*)&aw2s[n*32 + ((g*8) ^ ((n&3)<<3))];
      lg[nt] = __builtin_amdgcn_mfma_f32_16x16x32_bf16(h2f, bf, cini, 0, 0, 0);
    }

    // V gather
    float vv[8][4];
#pragma unroll
    for (int r = 0; r < 4; ++r) {
      const float* vrow = vws + (size_t)((b<<12) + idr[r])*DIM;
#pragma unroll
      for (int nt = 0; nt < 8; ++nt) vv[nt][r] = vrow[nt*16 + c16];
    }

    // per-column softmax over 16 rows + weighted sum of (v + pe + pb2)
#pragma unroll
    for (int nt = 0; nt < 8; ++nt) {
      float m = fmaxf(fmaxf(lg[nt][0], lg[nt][1]), fmaxf(lg[nt][2], lg[nt][3]));
      m = fmaxf(m, __shfl_xor(m, 16));
      m = fmaxf(m, __shfl_xor(m, 32));
      float e0 = __expf(lg[nt][0]-m), e1 = __expf(lg[nt][1]-m),
            e2 = __expf(lg[nt][2]-m), e3 = __expf(lg[nt][3]-m);
      float s = e0+e1+e2+e3;
      s += __shfl_xor(s, 16);
      s += __shfl_xor(s, 32);
      float inv = 1.0f / s;
      float pb = pb2s[nt*16 + c16];
      float acc = e0*(vv[nt][0] + pe[nt][0] + pb)
                + e1*(vv[nt][1] + pe[nt][1] + pb)
                + e2*(vv[nt][2] + pe[nt][2] + pb)
                + e3*(vv[nt][3] + pe[nt][3] + pb);
      acc *= inv;
      acc += __shfl_xor(acc, 16);
      acc += __shfl_xor(acc, 32);
      if (lane < 16) out[q*DIM + nt*16 + lane] = acc;
    }
  }
}

// ---------------- launch ----------------
extern "C" void kernel_launch(void* const* d_in, const int* in_sizes, int n_in,
                              void* d_out, int out_size, void* d_ws, size_t ws_size,
                              hipStream_t stream) {
  const float* x   = (const float*)d_in[0];
  const float* pos = (const float*)d_in[1];
  const float* pw1 = (const float*)d_in[2];
  const float* pb1 = (const float*)d_in[3];
  const float* pw2 = (const float*)d_in[4];
  const float* pb2 = (const float*)d_in[5];
  const float* qw  = (const float*)d_in[6];
  const float* qb  = (const float*)d_in[7];
  const float* kw  = (const float*)d_in[8];
  const float* kb  = (const float*)d_in[9];
  const float* vw  = (const float*)d_in[10];
  const float* vb  = (const float*)d_in[11];
  const float* aw1 = (const float*)d_in[12];
  const float* ab1 = (const float*)d_in[13];
  const float* aw2 = (const float*)d_in[14];
  const float* ab2 = (const float*)d_in[15];
  float* out = (float*)d_out;

  char* ws = (char*)d_ws;
  float4* pos4   = (float4*)(ws);                       // 256 KB
  int*    knnIdx = (int*)(ws + (1u<<20));               // 1 MB
  u32*    part   = (u32*)(ws + (2u<<20));               // 16 MB (dead after refine)
  float*  vws    = (float*)(ws + (2u<<20));             // 8 MB (reuse)
  float*  qa     = (float*)(ws + (11u<<20));            // 2 MB
  float*  ka     = (float*)(ws + (13u<<20));            // 2 MB
  char*   wsw    = ws + (19u<<20);                      // weights region
  u16*    pw2T  = (u16*)(wsw);                          // 32 KB
  u16*    w1T   = (u16*)(wsw + 32768);                  // 8 KB
  u16*    aw2T  = (u16*)(wsw + 40960);                  // 8 KB
  float4* pw1q  = (float4*)(wsw + 49152);               // 2 KB
  float*  bias1 = (float*)(wsw + 51200);                // 128 B
  float*  Wq2   = (float*)(wsw + 51328);                // 16 KB
  float*  Wk2   = (float*)(wsw + 67712);                // 16 KB

  prep_pos4<<<NROWS/256, 256, 0, stream>>>(pos, pos4);
  prep_matmul<<<12, 256, 0, stream>>>(pw2, qw, kw, aw1, w1T, Wq2, Wk2);
  prep_convert<<<81, 256, 0, stream>>>(pw2, aw2, pw1, pb1, qb, kb, pb2, aw1, ab1,
                                       pw2T, aw2T, pw1q, bias1);
  knn_scan<<<(NROWS/64)*NCHUNK/4, 256, 0, stream>>>(pos4, part);
  knn_refine<<<NROWS/16, 256, 0, stream>>>(pos4, part, knnIdx);
  proj_v<<<NROWS/32, 256, 0, stream>>>(x, vw, vb, Wq2, Wk2, vws, qa, ka);
  attn_mfma<<<NROWS/64, 1024, 0, stream>>>(pos4, knnIdx, vws, qa, ka,
                                           pw2T, w1T, aw2T, pw1q, bias1, pb2, ab2, out);
}

// Round 11
// 261.328 us; speedup vs baseline: 1.0197x; 1.0197x over previous
//
#include <hip/hip_runtime.h>
#include <hip/hip_bf16.h>
#include <stdint.h>

#define BATCH 4
#define NPTS  4096
#define DIM   128
#define KNN   16
#define NROWS (BATCH*NPTS)   // 16384
#define NCHUNK 16
#define CHUNK  (NPTS/NCHUNK) // 256

typedef unsigned long long u64;
typedef unsigned int u32;
typedef unsigned short u16;
typedef __attribute__((ext_vector_type(8))) short short8;
typedef __attribute__((ext_vector_type(4))) float f32x4;

__device__ __forceinline__ u16 f2bf(float f) {
  u32 u = __float_as_uint(f);
  u += 0x7FFFu + ((u >> 16) & 1);   // RNE
  return (u16)(u >> 16);
}

// wave-internal LDS fence (cross-lane visibility of same-wave DS stores)
#define WAVE_LDS_FENCE() asm volatile("s_waitcnt lgkmcnt(0)" ::: "memory")

// ---------------- ONE merged prep kernel ----------------
// bid: [0,64) pw2T | [64,80) aw2T | [80,144) vwT | 144 pw1q+bias1
//      [145,157) folded matmuls (w1T/Wq2T/Wk2T, bf16 images) | [157,221) pos4
__global__ __launch_bounds__(256) void prep_all(
    const float* __restrict__ pos,
    const float* __restrict__ pw1, const float* __restrict__ pb1,
    const float* __restrict__ pw2, const float* __restrict__ pb2,
    const float* __restrict__ qw, const float* __restrict__ qb,
    const float* __restrict__ kw, const float* __restrict__ kb,
    const float* __restrict__ vw,
    const float* __restrict__ aw1, const float* __restrict__ ab1,
    const float* __restrict__ aw2,
    float4* __restrict__ pos4, u16* __restrict__ pw2T, u16* __restrict__ aw2T,
    u16* __restrict__ vwT, u16* __restrict__ w1T,
    u16* __restrict__ Wq2T, u16* __restrict__ Wk2T,
    float4* __restrict__ pw1q, float* __restrict__ bias1) {
  const int bid = blockIdx.x, tid = threadIdx.x;
  if (bid < 64) {
    int e = bid*256 + tid, k = e >> 7, n = e & 127;
    pw2T[n*128 + (k ^ ((n&7)<<3))] = f2bf(pw2[k*128 + n]);
  } else if (bid < 80) {
    int e = (bid-64)*256 + tid, k = e >> 7, n = e & 127;
    aw2T[n*32 + (k ^ ((n&3)<<3))] = f2bf(aw2[k*128 + n]);
  } else if (bid < 144) {
    int e = (bid-80)*256 + tid, k = e >> 7, n = e & 127;
    vwT[n*128 + (k ^ ((n&7)<<3))] = f2bf(vw[k*128 + n]);
  } else if (bid == 144) {
    if (tid < 128) {
      int c = tid;
      pw1q[c ^ ((c & 0x18) >> 2)] = make_float4(pw1[c], pw1[128+c], pw1[256+c], pb1[c]);
    } else if (tid < 160) {
      int j = tid - 128;
      float s = ab1[j];
      for (int c = 0; c < 128; ++c) s += (qb[c]-kb[c]+pb2[c]) * aw1[c*32+j];
      bias1[j] = s;
    }
  } else if (bid < 157) {
    int p = (bid-145) >> 2, qtr = (bid-145) & 3;
    const float* A = p == 0 ? pw2 : (p == 1 ? qw : kw);
    int j = tid & 31, r0 = qtr*32 + (tid >> 5)*4;
    float acc[4] = {0.f,0.f,0.f,0.f};
    for (int c = 0; c < 128; ++c) {
      float av = aw1[c*32 + j];
#pragma unroll
      for (int rr = 0; rr < 4; ++rr) acc[rr] = fmaf(A[(r0+rr)*128 + c], av, acc[rr]);
    }
#pragma unroll
    for (int rr = 0; rr < 4; ++rr) {
      int h = r0 + rr;
      u16 v = f2bf(acc[rr]);
      if (p == 0)      w1T [j*128 + (h ^ ((j&7)<<3))] = v;
      else if (p == 1) Wq2T[j*128 + (h ^ ((j&7)<<3))] = v;
      else             Wk2T[j*128 + (h ^ ((j&7)<<3))] = v;
    }
  } else {
    int i = (bid-157)*256 + tid;
    if (i < NROWS) pos4[i] = make_float4(pos[3*i], pos[3*i+1], pos[3*i+2], 0.f);
  }
}

// ---------------- branchless sorting primitives ----------------
template <typename T>
__device__ __forceinline__ void cex(T& a, T& b) {
  T mn = a < b ? a : b;
  T mx = a < b ? b : a;
  a = mn; b = mx;
}
template <typename T>
__device__ __forceinline__ void sort16(T x[16]) {
#pragma unroll
  for (int k = 2; k <= 16; k <<= 1)
#pragma unroll
    for (int j = k >> 1; j > 0; j >>= 1)
#pragma unroll
      for (int i = 0; i < 16; ++i) {
        int l = i ^ j;
        if (l > i) { if ((i & k) == 0) cex(x[i], x[l]); else cex(x[l], x[i]); }
      }
}
template <typename T>
__device__ __forceinline__ void merge16(T A[16], const T B[16]) {
#pragma unroll
  for (int i = 0; i < 16; ++i) { T b = B[15 - i]; A[i] = A[i] < b ? A[i] : b; }
#pragma unroll
  for (int j = 8; j > 0; j >>= 1)
#pragma unroll
    for (int i = 0; i < 16; ++i) { int l = i ^ j; if (l > i) cex(A[i], A[l]); }
}
__device__ __forceinline__ void bmerge32(u32 x[32]) {
#pragma unroll
  for (int j = 16; j > 0; j >>= 1)
#pragma unroll
    for (int i = 0; i < 32; ++i) { int l = i ^ j; if (l > i) cex(x[i], x[l]); }
}

// ---------------- kNN pass 1 (+exact batch-skip vote) ----------------
__global__ __launch_bounds__(256) void knn_scan(const float4* __restrict__ pos4,
                                                u32* __restrict__ part) {
  __shared__ float4 cs[4][CHUNK];
  const int lane  = threadIdx.x & 63;
  const int w     = threadIdx.x >> 6;
  const int task  = blockIdx.x * 4 + w;
  const int qg    = task >> 4;
  const int chunk = task & 15;
  const int qbase = qg * 64;
  const int b     = qbase >> 12;
  const int cbase = chunk * CHUNK;

  const float4* cand = pos4 + b*NPTS + cbase;
#pragma unroll
  for (int i = 0; i < CHUNK/64; ++i) cs[w][lane + 64*i] = cand[lane + 64*i];
  __syncthreads();

  float4 qp = pos4[qbase + lane];
  const float qx = qp.x, qy = qp.y, qz = qp.z;

  u32 best[16];
#pragma unroll
  for (int i = 0; i < 16; ++i) best[i] = ~0u;

#pragma unroll 1
  for (int m = 0; m < CHUNK/16; ++m) {
    u32 batch[16];
#pragma unroll
    for (int e = 0; e < 16; ++e) {
      float4 p = cs[w][m*16 + e];
      float dx = qx - p.x, dy = qy - p.y, dz = qz - p.z;
      float d  = fmaf(dx, dx, fmaf(dy, dy, dz*dz));
      batch[e] = (__float_as_uint(d) & 0xFFFFF000u) | (u32)(cbase + m*16 + e);
    }
    // exact skip: batch contributes iff some key < current 16th-best
    u32 bmin = batch[0];
#pragma unroll
    for (int e = 1; e < 16; ++e) bmin = batch[e] < bmin ? batch[e] : bmin;
    if (__any(bmin < best[15])) {
      sort16(batch);
      merge16(best, batch);
    }
  }
  const int q = qbase + lane;
  uint4* dst = (uint4*)(part + q*256 + chunk*16);
#pragma unroll
  for (int t = 0; t < 4; ++t)
    dst[t] = make_uint4(best[4*t], best[4*t+1], best[4*t+2], best[4*t+3]);
}

// ---------------- kNN pass 2 (unchanged) ----------------
__global__ __launch_bounds__(256) void knn_refine(const float4* __restrict__ pos4,
                                                  const u32* __restrict__ part,
                                                  int* __restrict__ knnIdx) {
  __shared__ u64 A64[16][137];
  __shared__ u32 Bu[16][264];
  u32 (*Au)[274] = (u32 (*)[274])A64;

  const int tid = threadIdx.x;
  const int qi = tid >> 4, c = tid & 15;
  const int q  = blockIdx.x * 16 + qi;
  const int b  = q >> 12;

  {
    const uint4* src = (const uint4*)(part + q*256 + c*16);
    u32 own[16];
#pragma unroll
    for (int t = 0; t < 4; ++t) {
      uint4 v = src[t];
      own[4*t+0]=v.x; own[4*t+1]=v.y; own[4*t+2]=v.z; own[4*t+3]=v.w;
    }
#pragma unroll
    for (int s = 0; s < 16; ++s) Au[qi][c*17 + s] = own[s];
  }
  __syncthreads();

  if (c < 8) {
    u32 x[32];
#pragma unroll
    for (int s = 0; s < 16; ++s) x[s]      = Au[qi][(2*c)*17 + s];
#pragma unroll
    for (int s = 0; s < 16; ++s) x[16 + s] = Au[qi][(2*c+1)*17 + 15 - s];
    bmerge32(x);
#pragma unroll
    for (int s = 0; s < 32; ++s) Bu[qi][c*33 + s] = x[s];
  }
  __syncthreads();

  if (c < 4) {
    u32 x[32];
#pragma unroll
    for (int s = 0; s < 32; ++s) {
      u32 a = Bu[qi][(2*c)*33 + s], bb = Bu[qi][(2*c+1)*33 + 31 - s];
      x[s] = a < bb ? a : bb;
    }
    bmerge32(x);
#pragma unroll
    for (int s = 0; s < 32; ++s) Au[qi][c*33 + s] = x[s];
  }
  __syncthreads();

  if (c < 2) {
    u32 x[32];
#pragma unroll
    for (int s = 0; s < 32; ++s) {
      u32 a = Au[qi][(2*c)*33 + s], bb = Au[qi][(2*c+1)*33 + 31 - s];
      x[s] = a < bb ? a : bb;
    }
    bmerge32(x);
#pragma unroll
    for (int s = 0; s < 32; ++s) Bu[qi][c*33 + s] = x[s];
  }
  __syncthreads();

  if (c == 0) {
    u32 x[32];
#pragma unroll
    for (int s = 0; s < 32; ++s) {
      u32 a = Bu[qi][s], bb = Bu[qi][33 + 31 - s];
      x[s] = a < bb ? a : bb;
    }
    bmerge32(x);
#pragma unroll
    for (int s = 0; s < 32; ++s) Bu[qi][132 + s] = x[s];
  }
  __syncthreads();

  if (c < 2) {
    float4 qp = pos4[q];
    const double qx = qp.x, qy = qp.y, qz = qp.z;
    u64 key[16];
#pragma unroll
    for (int s = 0; s < 16; ++s) {
      int idx = (int)(Bu[qi][132 + c*16 + s] & 0xFFFu);
      float4 p = pos4[(b<<12) + idx];
      double dx = qx - (double)p.x;
      double dy = qy - (double)p.y;
      double dz = qz - (double)p.z;
      double d  = fma(dx, dx, fma(dy, dy, dz*dz));
      key[s] = (((u64)__double_as_longlong(d)) & ~0xFFFull) | (u64)idx;
    }
    sort16(key);
#pragma unroll
    for (int s = 0; s < 16; ++s) A64[qi][c*17 + s] = key[s];
  }
  __syncthreads();

  if (c == 0) {
    u64 best[16], nb[16];
#pragma unroll
    for (int s = 0; s < 16; ++s) { best[s] = A64[qi][s]; nb[s] = A64[qi][17 + s]; }
    merge16(best, nb);
    const int outq = q * KNN;
#pragma unroll
    for (int s = 0; s < 16; ++s) knnIdx[outq + s] = (int)(best[s] & 0xFFFull);
  }
}

// ---------------- proj via MFMA: V + qa + ka (bf16 in, fp32 out) ----------------
__global__ __launch_bounds__(256) void proj_mfma(
    const float* __restrict__ x, const u16* __restrict__ vwT,
    const u16* __restrict__ Wq2T, const u16* __restrict__ Wk2T,
    const float* __restrict__ vb,
    float* __restrict__ vo, float* __restrict__ qa, float* __restrict__ ka) {
  const int lane = threadIdx.x & 63, w = threadIdx.x >> 6;
  const int c16 = lane & 15, g = lane >> 4;
  const int row0 = (blockIdx.x*4 + w)*16;

  // A-frags: lane holds row=row0+c16, k = kc*32 + g*8 + j  (proven layout)
  const float* xrow = x + (size_t)(row0 + c16)*DIM;
  short8 af[4];
#pragma unroll
  for (int kc = 0; kc < 4; ++kc) {
    float4 a0 = *(const float4*)&xrow[kc*32 + g*8];
    float4 a1 = *(const float4*)&xrow[kc*32 + g*8 + 4];
    short8 s;
    s[0]=(short)f2bf(a0.x); s[1]=(short)f2bf(a0.y); s[2]=(short)f2bf(a0.z); s[3]=(short)f2bf(a0.w);
    s[4]=(short)f2bf(a1.x); s[5]=(short)f2bf(a1.y); s[6]=(short)f2bf(a1.z); s[7]=(short)f2bf(a1.w);
    af[kc] = s;
  }

  // V = x @ vw + vb
#pragma unroll
  for (int nt = 0; nt < 8; ++nt) {
    int n = nt*16 + c16;
    float bb = vb[n];
    f32x4 acc = {bb, bb, bb, bb};
#pragma unroll
    for (int kc = 0; kc < 4; ++kc) {
      short8 bf = *(const short8*)&vwT[n*128 + ((kc*32 + g*8) ^ ((n&7)<<3))];
      acc = __builtin_amdgcn_mfma_f32_16x16x32_bf16(af[kc], bf, acc, 0, 0, 0);
    }
#pragma unroll
    for (int r = 0; r < 4; ++r)
      vo[(size_t)(row0 + g*4 + r)*DIM + n] = acc[r];
  }

  // qa = x @ Wq2, ka = x @ Wk2 (no bias; folded into bias1)
#pragma unroll
  for (int t = 0; t < 2; ++t) {
    int n = t*16 + c16;
    f32x4 aq = {0.f,0.f,0.f,0.f}, ak = {0.f,0.f,0.f,0.f};
#pragma unroll
    for (int kc = 0; kc < 4; ++kc) {
      short8 bq = *(const short8*)&Wq2T[n*128 + ((kc*32 + g*8) ^ ((n&7)<<3))];
      short8 bk = *(const short8*)&Wk2T[n*128 + ((kc*32 + g*8) ^ ((n&7)<<3))];
      aq = __builtin_amdgcn_mfma_f32_16x16x32_bf16(af[kc], bq, aq, 0, 0, 0);
      ak = __builtin_amdgcn_mfma_f32_16x16x32_bf16(af[kc], bk, ak, 0, 0, 0);
    }
#pragma unroll
    for (int r = 0; r < 4; ++r) {
      qa[(row0 + g*4 + r)*32 + n] = aq[r];
      ka[(row0 + g*4 + r)*32 + n] = ak[r];
    }
  }
}

// ---------------- fused MFMA attention: 4 waves/block, 4q/wave, 1024 blocks ----------------
__global__ __launch_bounds__(256, 4) void attn_mfma(
    const float4* __restrict__ pos4, const int* __restrict__ knnIdx,
    const float* __restrict__ vws, const float* __restrict__ qa, const float* __restrict__ ka,
    const u16* __restrict__ pw2T, const u16* __restrict__ w1T, const u16* __restrict__ aw2T,
    const float4* __restrict__ pw1q, const float* __restrict__ bias1,
    const float* __restrict__ pb2, const float* __restrict__ ab2,
    float* __restrict__ out) {
  __shared__ __align__(16) u16 pw2s[16384];   // 32 KB
  __shared__ __align__(16) float4 pw1s[128];  // 2 KB
  __shared__ float bias1s[32], pb2s[128], ab2s[128];
  __shared__ __align__(16) u16 h2t[4][512];   // per-wave, 4 KB
  // total ~39.2 KB -> 4 blocks/CU (16 waves/CU)

  const int tid = threadIdx.x;
  {
    const uint4* s1 = (const uint4*)pw2T; uint4* d1 = (uint4*)pw2s;
#pragma unroll
    for (int i = 0; i < 8; ++i) d1[tid + 256*i] = s1[tid + 256*i];
    if (tid < 128) { pw1s[tid] = pw1q[tid]; pb2s[tid] = pb2[tid]; ab2s[tid] = ab2[tid]; }
    else if (tid < 160) bias1s[tid-128] = bias1[tid-128];
  }
  __syncthreads();   // only block barrier

  const int lane = tid & 63, w = tid >> 6;
  const int c16 = lane & 15, g = lane >> 4;

  // per-wave register B-fragments (loaded once from L2-hot images)
  short8 Bw1[4][2];
#pragma unroll
  for (int kc = 0; kc < 4; ++kc)
#pragma unroll
    for (int t = 0; t < 2; ++t) {
      int n = t*16 + c16;
      Bw1[kc][t] = *(const short8*)&w1T[n*128 + ((kc*32 + g*8) ^ ((n&7)<<3))];
    }
  short8 Baw2[8];
#pragma unroll
  for (int nt = 0; nt < 8; ++nt) {
    int n = nt*16 + c16;
    Baw2[nt] = *(const short8*)&aw2T[n*32 + ((g*8) ^ ((n&3)<<3))];
  }

  // XCD-aware bijective swizzle: 1024 blocks, XCD x owns a contiguous query range
  const int swz = (blockIdx.x & 7) * 128 + (blockIdx.x >> 3);
  const int qblock = swz * 16;
  const int qbase  = qblock + w * 4;
  const int bofs   = (qblock >> 12) << 12;

  // coalesced neighbor metadata: lane (qL = lane>>4, k = lane&15)
  int id_own = knnIdx[qbase*KNN + lane];          // = (qbase+qL)*16 + k
  float4 pq = pos4[qbase + g];
  float4 pn = pos4[bofs + id_own];
  float rox = pq.x - pn.x, roy = pq.y - pn.y, roz = pq.z - pn.z;

#pragma unroll
  for (int j = 0; j < 4; ++j) {
    const int q = qbase + j;
    // shfl-broadcast this query's rel/id data (no LDS, no fence)
    float relx = __shfl(rox, j*16 + c16);
    float rely = __shfl(roy, j*16 + c16);
    float relz = __shfl(roz, j*16 + c16);
    int idr[4];
#pragma unroll
    for (int r = 0; r < 4; ++r) idr[r] = __shfl(id_own, j*16 + g*4 + r);

    // early gathers
    float qa_v[2], ka_v[2][4];
#pragma unroll
    for (int t = 0; t < 2; ++t) qa_v[t] = qa[q*32 + t*16 + c16];
#pragma unroll
    for (int r = 0; r < 4; ++r)
#pragma unroll
      for (int t = 0; t < 2; ++t) ka_v[t][r] = ka[(bofs + idr[r])*32 + t*16 + c16];

    // h1 in A-fragment layout
    short8 h1f[4];
#pragma unroll
    for (int kc = 0; kc < 4; ++kc) {
      short8 s;
#pragma unroll
      for (int jj = 0; jj < 8; ++jj) {
        int c = kc*32 + g*8 + jj;
        float4 wv = pw1s[c ^ ((c & 0x18) >> 2)];
        float h = fmaf(relx, wv.x, fmaf(rely, wv.y, fmaf(relz, wv.z, wv.w)));
        s[jj] = (short)f2bf(fmaxf(h, 0.f));
      }
      h1f[kc] = s;
    }

    // pe = h1 @ pw2 (B from LDS)
    f32x4 pe[8];
#pragma unroll
    for (int nt = 0; nt < 8; ++nt) { f32x4 z = {0.f,0.f,0.f,0.f}; pe[nt] = z; }
#pragma unroll
    for (int kc = 0; kc < 4; ++kc)
#pragma unroll
      for (int nt = 0; nt < 8; ++nt) {
        int n = nt*16 + c16;
        short8 bf = *(const short8*)&pw2s[n*128 + ((kc*32 + g*8) ^ ((n&7)<<3))];
        pe[nt] = __builtin_amdgcn_mfma_f32_16x16x32_bf16(h1f[kc], bf, pe[nt], 0, 0, 0);
      }

    // ha = h1 @ W1 (B from registers)
    f32x4 ha[2];
#pragma unroll
    for (int t = 0; t < 2; ++t) { f32x4 z = {0.f,0.f,0.f,0.f}; ha[t] = z; }
#pragma unroll
    for (int kc = 0; kc < 4; ++kc)
#pragma unroll
      for (int t = 0; t < 2; ++t)
        ha[t] = __builtin_amdgcn_mfma_f32_16x16x32_bf16(h1f[kc], Bw1[kc][t], ha[t], 0, 0, 0);

    // h2 = relu(ha + qa - ka + bias1) -> bf16 -> per-wave LDS (C->A layout round-trip)
#pragma unroll
    for (int t = 0; t < 2; ++t)
#pragma unroll
      for (int r = 0; r < 4; ++r) {
        float v = ha[t][r] + qa_v[t] - ka_v[t][r] + bias1s[t*16 + c16];
        int row = g*4 + r, col = t*16 + c16;
        h2t[w][row*32 + (col ^ ((row&3)<<3))] = f2bf(fmaxf(v, 0.f));
      }
    WAVE_LDS_FENCE();

    short8 h2f = *(const short8*)&h2t[w][c16*32 + ((g*8) ^ ((c16&3)<<3))];

    // logits = h2 @ aw2 + ab2 (B from registers)
    f32x4 lg[8];
#pragma unroll
    for (int nt = 0; nt < 8; ++nt) {
      float ab = ab2s[nt*16 + c16];
      f32x4 cini = {ab, ab, ab, ab};
      lg[nt] = __builtin_amdgcn_mfma_f32_16x16x32_bf16(h2f, Baw2[nt], cini, 0, 0, 0);
    }

    // per-column softmax + weighted sum of (V + pe + pb2); V just-in-time from L2
#pragma unroll
    for (int nt = 0; nt < 8; ++nt) {
      float m = fmaxf(fmaxf(lg[nt][0], lg[nt][1]), fmaxf(lg[nt][2], lg[nt][3]));
      m = fmaxf(m, __shfl_xor(m, 16));
      m = fmaxf(m, __shfl_xor(m, 32));
      float e0 = __expf(lg[nt][0]-m), e1 = __expf(lg[nt][1]-m),
            e2 = __expf(lg[nt][2]-m), e3 = __expf(lg[nt][3]-m);
      float s = e0+e1+e2+e3;
      s += __shfl_xor(s, 16);
      s += __shfl_xor(s, 32);
      float inv = 1.0f / s;
      float pb = pb2s[nt*16 + c16];
      float v0 = vws[(size_t)(bofs + idr[0])*DIM + nt*16 + c16];
      float v1 = vws[(size_t)(bofs + idr[1])*DIM + nt*16 + c16];
      float v2 = vws[(size_t)(bofs + idr[2])*DIM + nt*16 + c16];
      float v3 = vws[(size_t)(bofs + idr[3])*DIM + nt*16 + c16];
      float acc = e0*(v0 + pe[nt][0] + pb)
                + e1*(v1 + pe[nt][1] + pb)
                + e2*(v2 + pe[nt][2] + pb)
                + e3*(v3 + pe[nt][3] + pb);
      acc *= inv;
      acc += __shfl_xor(acc, 16);
      acc += __shfl_xor(acc, 32);
      if (lane < 16) out[q*DIM + nt*16 + lane] = acc;
    }
  }
}

// ---------------- launch ----------------
extern "C" void kernel_launch(void* const* d_in, const int* in_sizes, int n_in,
                              void* d_out, int out_size, void* d_ws, size_t ws_size,
                              hipStream_t stream) {
  const float* x   = (const float*)d_in[0];
  const float* pos = (const float*)d_in[1];
  const float* pw1 = (const float*)d_in[2];
  const float* pb1 = (const float*)d_in[3];
  const float* pw2 = (const float*)d_in[4];
  const float* pb2 = (const float*)d_in[5];
  const float* qw  = (const float*)d_in[6];
  const float* qb  = (const float*)d_in[7];
  const float* kw  = (const float*)d_in[8];
  const float* kb  = (const float*)d_in[9];
  const float* vw  = (const float*)d_in[10];
  const float* vb  = (const float*)d_in[11];
  const float* aw1 = (const float*)d_in[12];
  const float* ab1 = (const float*)d_in[13];
  const float* aw2 = (const float*)d_in[14];
  const float* ab2 = (const float*)d_in[15];
  float* out = (float*)d_out;

  char* ws = (char*)d_ws;
  float4* pos4   = (float4*)(ws);                       // 256 KB
  int*    knnIdx = (int*)(ws + (1u<<20));               // 1 MB
  u32*    part   = (u32*)(ws + (2u<<20));               // 16 MB (dead after refine)
  float*  vws    = (float*)(ws + (2u<<20));             // 8 MB (reuse)
  float*  qa     = (float*)(ws + (11u<<20));            // 2 MB
  float*  ka     = (float*)(ws + (13u<<20));            // 2 MB
  char*   wsw    = ws + (19u<<20);                      // weights region
  u16*    pw2T  = (u16*)(wsw);                          // 32 KB
  u16*    w1T   = (u16*)(wsw + 32768);                  // 8 KB
  u16*    aw2T  = (u16*)(wsw + 40960);                  // 8 KB
  u16*    vwT   = (u16*)(wsw + 49152);                  // 32 KB
  u16*    Wq2T  = (u16*)(wsw + 81920);                  // 8 KB
  u16*    Wk2T  = (u16*)(wsw + 90112);                  // 8 KB
  float4* pw1q  = (float4*)(wsw + 98304);               // 2 KB
  float*  bias1 = (float*)(wsw + 100352);               // 128 B

  prep_all<<<221, 256, 0, stream>>>(pos, pw1, pb1, pw2, pb2, qw, qb, kw, kb, vw,
                                    aw1, ab1, aw2,
                                    pos4, pw2T, aw2T, vwT, w1T, Wq2T, Wk2T, pw1q, bias1);
  knn_scan<<<(NROWS/64)*NCHUNK/4, 256, 0, stream>>>(pos4, part);
  knn_refine<<<NROWS/16, 256, 0, stream>>>(pos4, part, knnIdx);
  proj_mfma<<<NROWS/64, 256, 0, stream>>>(x, vwT, Wq2T, Wk2T, vb, vws, qa, ka);
  attn_mfma<<<NROWS/16, 256, 0, stream>>>(pos4, knnIdx, vws, qa, ka,
                                          pw2T, w1T, aw2T, pw1q, bias1, pb2, ab2, out);
}

// Round 12
// 239.651 us; speedup vs baseline: 1.1120x; 1.0904x over previous
//
#include <hip/hip_runtime.h>
#include <hip/hip_bf16.h>
#include <stdint.h>

#define BATCH 4
#define NPTS  4096
#define DIM   128
#define KNN   16
#define NROWS (BATCH*NPTS)   // 16384
#define NCHUNK 16
#define CHUNK  (NPTS/NCHUNK) // 256

typedef unsigned long long u64;
typedef unsigned int u32;
typedef unsigned short u16;
typedef __attribute__((ext_vector_type(8))) short short8;
typedef __attribute__((ext_vector_type(4))) float f32x4;

__device__ __forceinline__ u16 f2bf(float f) {
  u32 u = __float_as_uint(f);
  u += 0x7FFFu + ((u >> 16) & 1);   // RNE
  return (u16)(u >> 16);
}

// wave-internal LDS fence (cross-lane visibility of same-wave DS stores)
#define WAVE_LDS_FENCE() asm volatile("s_waitcnt lgkmcnt(0)" ::: "memory")

// ---------------- ONE merged prep kernel ----------------
__global__ __launch_bounds__(256) void prep_all(
    const float* __restrict__ pos,
    const float* __restrict__ pw1, const float* __restrict__ pb1,
    const float* __restrict__ pw2, const float* __restrict__ pb2,
    const float* __restrict__ qw, const float* __restrict__ qb,
    const float* __restrict__ kw, const float* __restrict__ kb,
    const float* __restrict__ vw,
    const float* __restrict__ aw1, const float* __restrict__ ab1,
    const float* __restrict__ aw2,
    float4* __restrict__ pos4, u16* __restrict__ pw2T, u16* __restrict__ aw2T,
    u16* __restrict__ vwT, u16* __restrict__ w1T,
    u16* __restrict__ Wq2T, u16* __restrict__ Wk2T,
    float4* __restrict__ pw1q, float* __restrict__ bias1) {
  const int bid = blockIdx.x, tid = threadIdx.x;
  if (bid < 64) {
    int e = bid*256 + tid, k = e >> 7, n = e & 127;
    pw2T[n*128 + (k ^ ((n&7)<<3))] = f2bf(pw2[k*128 + n]);
  } else if (bid < 80) {
    int e = (bid-64)*256 + tid, k = e >> 7, n = e & 127;
    aw2T[n*32 + (k ^ ((n&3)<<3))] = f2bf(aw2[k*128 + n]);
  } else if (bid < 144) {
    int e = (bid-80)*256 + tid, k = e >> 7, n = e & 127;
    vwT[n*128 + (k ^ ((n&7)<<3))] = f2bf(vw[k*128 + n]);
  } else if (bid == 144) {
    if (tid < 128) {
      int c = tid;
      pw1q[c ^ ((c & 0x18) >> 2)] = make_float4(pw1[c], pw1[128+c], pw1[256+c], pb1[c]);
    } else if (tid < 160) {
      int j = tid - 128;
      float s = ab1[j];
      for (int c = 0; c < 128; ++c) s += (qb[c]-kb[c]+pb2[c]) * aw1[c*32+j];
      bias1[j] = s;
    }
  } else if (bid < 157) {
    int p = (bid-145) >> 2, qtr = (bid-145) & 3;
    const float* A = p == 0 ? pw2 : (p == 1 ? qw : kw);
    int j = tid & 31, r0 = qtr*32 + (tid >> 5)*4;
    float acc[4] = {0.f,0.f,0.f,0.f};
    for (int c = 0; c < 128; ++c) {
      float av = aw1[c*32 + j];
#pragma unroll
      for (int rr = 0; rr < 4; ++rr) acc[rr] = fmaf(A[(r0+rr)*128 + c], av, acc[rr]);
    }
#pragma unroll
    for (int rr = 0; rr < 4; ++rr) {
      int h = r0 + rr;
      u16 v = f2bf(acc[rr]);
      if (p == 0)      w1T [j*128 + (h ^ ((j&7)<<3))] = v;
      else if (p == 1) Wq2T[j*128 + (h ^ ((j&7)<<3))] = v;
      else             Wk2T[j*128 + (h ^ ((j&7)<<3))] = v;
    }
  } else {
    int i = (bid-157)*256 + tid;
    if (i < NROWS) pos4[i] = make_float4(pos[3*i], pos[3*i+1], pos[3*i+2], 0.f);
  }
}

// ---------------- branchless sorting primitives ----------------
template <typename T>
__device__ __forceinline__ void cex(T& a, T& b) {
  T mn = a < b ? a : b;
  T mx = a < b ? b : a;
  a = mn; b = mx;
}
template <typename T>
__device__ __forceinline__ void sort16(T x[16]) {
#pragma unroll
  for (int k = 2; k <= 16; k <<= 1)
#pragma unroll
    for (int j = k >> 1; j > 0; j >>= 1)
#pragma unroll
      for (int i = 0; i < 16; ++i) {
        int l = i ^ j;
        if (l > i) { if ((i & k) == 0) cex(x[i], x[l]); else cex(x[l], x[i]); }
      }
}
template <typename T>
__device__ __forceinline__ void merge16(T A[16], const T B[16]) {
#pragma unroll
  for (int i = 0; i < 16; ++i) { T b = B[15 - i]; A[i] = A[i] < b ? A[i] : b; }
#pragma unroll
  for (int j = 8; j > 0; j >>= 1)
#pragma unroll
    for (int i = 0; i < 16; ++i) { int l = i ^ j; if (l > i) cex(A[i], A[l]); }
}
__device__ __forceinline__ void bmerge32(u32 x[32]) {
#pragma unroll
  for (int j = 16; j > 0; j >>= 1)
#pragma unroll
    for (int i = 0; i < 32; ++i) { int l = i ^ j; if (l > i) cex(x[i], x[l]); }
}

// ---------------- kNN pass 1 (+exact batch-skip vote) ----------------
__global__ __launch_bounds__(256) void knn_scan(const float4* __restrict__ pos4,
                                                u32* __restrict__ part) {
  __shared__ float4 cs[4][CHUNK];
  const int lane  = threadIdx.x & 63;
  const int w     = threadIdx.x >> 6;
  const int task  = blockIdx.x * 4 + w;
  const int qg    = task >> 4;
  const int chunk = task & 15;
  const int qbase = qg * 64;
  const int b     = qbase >> 12;
  const int cbase = chunk * CHUNK;

  const float4* cand = pos4 + b*NPTS + cbase;
#pragma unroll
  for (int i = 0; i < CHUNK/64; ++i) cs[w][lane + 64*i] = cand[lane + 64*i];
  __syncthreads();

  float4 qp = pos4[qbase + lane];
  const float qx = qp.x, qy = qp.y, qz = qp.z;

  u32 best[16];
#pragma unroll
  for (int i = 0; i < 16; ++i) best[i] = ~0u;

#pragma unroll 1
  for (int m = 0; m < CHUNK/16; ++m) {
    u32 batch[16];
#pragma unroll
    for (int e = 0; e < 16; ++e) {
      float4 p = cs[w][m*16 + e];
      float dx = qx - p.x, dy = qy - p.y, dz = qz - p.z;
      float d  = fmaf(dx, dx, fmaf(dy, dy, dz*dz));
      batch[e] = (__float_as_uint(d) & 0xFFFFF000u) | (u32)(cbase + m*16 + e);
    }
    u32 bmin = batch[0];
#pragma unroll
    for (int e = 1; e < 16; ++e) bmin = batch[e] < bmin ? batch[e] : bmin;
    if (__any(bmin < best[15])) {
      sort16(batch);
      merge16(best, batch);
    }
  }
  const int q = qbase + lane;
  uint4* dst = (uint4*)(part + q*256 + chunk*16);
#pragma unroll
  for (int t = 0; t < 4; ++t)
    dst[t] = make_uint4(best[4*t], best[4*t+1], best[4*t+2], best[4*t+3]);
}

// ---------------- kNN pass 2 (unchanged) ----------------
__global__ __launch_bounds__(256) void knn_refine(const float4* __restrict__ pos4,
                                                  const u32* __restrict__ part,
                                                  int* __restrict__ knnIdx) {
  __shared__ u64 A64[16][137];
  __shared__ u32 Bu[16][264];
  u32 (*Au)[274] = (u32 (*)[274])A64;

  const int tid = threadIdx.x;
  const int qi = tid >> 4, c = tid & 15;
  const int q  = blockIdx.x * 16 + qi;
  const int b  = q >> 12;

  {
    const uint4* src = (const uint4*)(part + q*256 + c*16);
    u32 own[16];
#pragma unroll
    for (int t = 0; t < 4; ++t) {
      uint4 v = src[t];
      own[4*t+0]=v.x; own[4*t+1]=v.y; own[4*t+2]=v.z; own[4*t+3]=v.w;
    }
#pragma unroll
    for (int s = 0; s < 16; ++s) Au[qi][c*17 + s] = own[s];
  }
  __syncthreads();

  if (c < 8) {
    u32 x[32];
#pragma unroll
    for (int s = 0; s < 16; ++s) x[s]      = Au[qi][(2*c)*17 + s];
#pragma unroll
    for (int s = 0; s < 16; ++s) x[16 + s] = Au[qi][(2*c+1)*17 + 15 - s];
    bmerge32(x);
#pragma unroll
    for (int s = 0; s < 32; ++s) Bu[qi][c*33 + s] = x[s];
  }
  __syncthreads();

  if (c < 4) {
    u32 x[32];
#pragma unroll
    for (int s = 0; s < 32; ++s) {
      u32 a = Bu[qi][(2*c)*33 + s], bb = Bu[qi][(2*c+1)*33 + 31 - s];
      x[s] = a < bb ? a : bb;
    }
    bmerge32(x);
#pragma unroll
    for (int s = 0; s < 32; ++s) Au[qi][c*33 + s] = x[s];
  }
  __syncthreads();

  if (c < 2) {
    u32 x[32];
#pragma unroll
    for (int s = 0; s < 32; ++s) {
      u32 a = Au[qi][(2*c)*33 + s], bb = Au[qi][(2*c+1)*33 + 31 - s];
      x[s] = a < bb ? a : bb;
    }
    bmerge32(x);
#pragma unroll
    for (int s = 0; s < 32; ++s) Bu[qi][c*33 + s] = x[s];
  }
  __syncthreads();

  if (c == 0) {
    u32 x[32];
#pragma unroll
    for (int s = 0; s < 32; ++s) {
      u32 a = Bu[qi][s], bb = Bu[qi][33 + 31 - s];
      x[s] = a < bb ? a : bb;
    }
    bmerge32(x);
#pragma unroll
    for (int s = 0; s < 32; ++s) Bu[qi][132 + s] = x[s];
  }
  __syncthreads();

  if (c < 2) {
    float4 qp = pos4[q];
    const double qx = qp.x, qy = qp.y, qz = qp.z;
    u64 key[16];
#pragma unroll
    for (int s = 0; s < 16; ++s) {
      int idx = (int)(Bu[qi][132 + c*16 + s] & 0xFFFu);
      float4 p = pos4[(b<<12) + idx];
      double dx = qx - (double)p.x;
      double dy = qy - (double)p.y;
      double dz = qz - (double)p.z;
      double d  = fma(dx, dx, fma(dy, dy, dz*dz));
      key[s] = (((u64)__double_as_longlong(d)) & ~0xFFFull) | (u64)idx;
    }
    sort16(key);
#pragma unroll
    for (int s = 0; s < 16; ++s) A64[qi][c*17 + s] = key[s];
  }
  __syncthreads();

  if (c == 0) {
    u64 best[16], nb[16];
#pragma unroll
    for (int s = 0; s < 16; ++s) { best[s] = A64[qi][s]; nb[s] = A64[qi][17 + s]; }
    merge16(best, nb);
    const int outq = q * KNN;
#pragma unroll
    for (int s = 0; s < 16; ++s) knnIdx[outq + s] = (int)(best[s] & 0xFFFull);
  }
}

// ---------------- proj via MFMA: V + qa + ka (bf16 in, fp32 out) ----------------
__global__ __launch_bounds__(256) void proj_mfma(
    const float* __restrict__ x, const u16* __restrict__ vwT,
    const u16* __restrict__ Wq2T, const u16* __restrict__ Wk2T,
    const float* __restrict__ vb,
    float* __restrict__ vo, float* __restrict__ qa, float* __restrict__ ka) {
  const int lane = threadIdx.x & 63, w = threadIdx.x >> 6;
  const int c16 = lane & 15, g = lane >> 4;
  const int row0 = (blockIdx.x*4 + w)*16;

  const float* xrow = x + (size_t)(row0 + c16)*DIM;
  short8 af[4];
#pragma unroll
  for (int kc = 0; kc < 4; ++kc) {
    float4 a0 = *(const float4*)&xrow[kc*32 + g*8];
    float4 a1 = *(const float4*)&xrow[kc*32 + g*8 + 4];
    short8 s;
    s[0]=(short)f2bf(a0.x); s[1]=(short)f2bf(a0.y); s[2]=(short)f2bf(a0.z); s[3]=(short)f2bf(a0.w);
    s[4]=(short)f2bf(a1.x); s[5]=(short)f2bf(a1.y); s[6]=(short)f2bf(a1.z); s[7]=(short)f2bf(a1.w);
    af[kc] = s;
  }

#pragma unroll
  for (int nt = 0; nt < 8; ++nt) {
    int n = nt*16 + c16;
    float bb = vb[n];
    f32x4 acc = {bb, bb, bb, bb};
#pragma unroll
    for (int kc = 0; kc < 4; ++kc) {
      short8 bf = *(const short8*)&vwT[n*128 + ((kc*32 + g*8) ^ ((n&7)<<3))];
      acc = __builtin_amdgcn_mfma_f32_16x16x32_bf16(af[kc], bf, acc, 0, 0, 0);
    }
#pragma unroll
    for (int r = 0; r < 4; ++r)
      vo[(size_t)(row0 + g*4 + r)*DIM + n] = acc[r];
  }

#pragma unroll
  for (int t = 0; t < 2; ++t) {
    int n = t*16 + c16;
    f32x4 aq = {0.f,0.f,0.f,0.f}, ak = {0.f,0.f,0.f,0.f};
#pragma unroll
    for (int kc = 0; kc < 4; ++kc) {
      short8 bq = *(const short8*)&Wq2T[n*128 + ((kc*32 + g*8) ^ ((n&7)<<3))];
      short8 bk = *(const short8*)&Wk2T[n*128 + ((kc*32 + g*8) ^ ((n&7)<<3))];
      aq = __builtin_amdgcn_mfma_f32_16x16x32_bf16(af[kc], bq, aq, 0, 0, 0);
      ak = __builtin_amdgcn_mfma_f32_16x16x32_bf16(af[kc], bk, ak, 0, 0, 0);
    }
#pragma unroll
    for (int r = 0; r < 4; ++r) {
      qa[(row0 + g*4 + r)*32 + n] = aq[r];
      ka[(row0 + g*4 + r)*32 + n] = ak[r];
    }
  }
}

// ---------------- fused MFMA attention: 4 waves/block, 4q/wave, 1024 blocks ----------------
// Register-pressure-aware: pe[8] is the only large live array. w1T/aw2T B-frags
// read at point of use from global (16 KB total -> L1-resident). lg per-nt.
__global__ __launch_bounds__(256, 4) void attn_mfma(
    const float4* __restrict__ pos4, const int* __restrict__ knnIdx,
    const float* __restrict__ vws, const float* __restrict__ qa, const float* __restrict__ ka,
    const u16* __restrict__ pw2T, const u16* __restrict__ w1T, const u16* __restrict__ aw2T,
    const float4* __restrict__ pw1q, const float* __restrict__ bias1,
    const float* __restrict__ pb2, const float* __restrict__ ab2,
    float* __restrict__ out) {
  __shared__ __align__(16) u16 pw2s[16384];   // 32 KB
  __shared__ __align__(16) float4 pw1s[128];  // 2 KB
  __shared__ float bias1s[32], pb2s[128], ab2s[128];
  __shared__ __align__(16) u16 h2t[4][512];   // per-wave, 4 KB
  // total ~39.5 KB -> 4 blocks/CU (16 waves/CU)

  const int tid = threadIdx.x;
  {
    const uint4* s1 = (const uint4*)pw2T; uint4* d1 = (uint4*)pw2s;
#pragma unroll
    for (int i = 0; i < 8; ++i) d1[tid + 256*i] = s1[tid + 256*i];
    if (tid < 128) { pw1s[tid] = pw1q[tid]; pb2s[tid] = pb2[tid]; ab2s[tid] = ab2[tid]; }
    else if (tid < 160) bias1s[tid-128] = bias1[tid-128];
  }
  __syncthreads();   // only block barrier

  const int lane = tid & 63, w = tid >> 6;
  const int c16 = lane & 15, g = lane >> 4;

  // XCD-aware bijective swizzle: 1024 blocks, XCD x owns a contiguous query range
  const int swz = (blockIdx.x & 7) * 128 + (blockIdx.x >> 3);
  const int qblock = swz * 16;
  const int qbase  = qblock + w * 4;
  const int bofs   = (qblock >> 12) << 12;

  // coalesced neighbor metadata: lane (qL = lane>>4, k = lane&15)
  int id_own = knnIdx[qbase*KNN + lane];
  float4 pq = pos4[qbase + g];
  float4 pn = pos4[bofs + id_own];
  float rox = pq.x - pn.x, roy = pq.y - pn.y, roz = pq.z - pn.z;

#pragma unroll 1
  for (int j = 0; j < 4; ++j) {
    const int q = qbase + j;
    float relx = __shfl(rox, j*16 + c16);
    float rely = __shfl(roy, j*16 + c16);
    float relz = __shfl(roz, j*16 + c16);
    int idr[4];
#pragma unroll
    for (int r = 0; r < 4; ++r) idr[r] = __shfl(id_own, j*16 + g*4 + r);

    // early gathers
    float qa_v[2], ka_v[2][4];
#pragma unroll
    for (int t = 0; t < 2; ++t) qa_v[t] = qa[q*32 + t*16 + c16];
#pragma unroll
    for (int r = 0; r < 4; ++r)
#pragma unroll
      for (int t = 0; t < 2; ++t) ka_v[t][r] = ka[(bofs + idr[r])*32 + t*16 + c16];

    // h1 in A-fragment layout
    short8 h1f[4];
#pragma unroll
    for (int kc = 0; kc < 4; ++kc) {
      short8 s;
#pragma unroll
      for (int jj = 0; jj < 8; ++jj) {
        int c = kc*32 + g*8 + jj;
        float4 wv = pw1s[c ^ ((c & 0x18) >> 2)];
        float h = fmaf(relx, wv.x, fmaf(rely, wv.y, fmaf(relz, wv.z, wv.w)));
        s[jj] = (short)f2bf(fmaxf(h, 0.f));
      }
      h1f[kc] = s;
    }

    // pe = h1 @ pw2 (B from LDS)
    f32x4 pe[8];
#pragma unroll
    for (int nt = 0; nt < 8; ++nt) { f32x4 z = {0.f,0.f,0.f,0.f}; pe[nt] = z; }
#pragma unroll
    for (int kc = 0; kc < 4; ++kc)
#pragma unroll
      for (int nt = 0; nt < 8; ++nt) {
        int n = nt*16 + c16;
        short8 bf = *(const short8*)&pw2s[n*128 + ((kc*32 + g*8) ^ ((n&7)<<3))];
        pe[nt] = __builtin_amdgcn_mfma_f32_16x16x32_bf16(h1f[kc], bf, pe[nt], 0, 0, 0);
      }

    // ha = h1 @ W1 (B point-of-use from global; w1T 8 KB is L1-resident)
    f32x4 ha[2];
#pragma unroll
    for (int t = 0; t < 2; ++t) { f32x4 z = {0.f,0.f,0.f,0.f}; ha[t] = z; }
#pragma unroll
    for (int kc = 0; kc < 4; ++kc)
#pragma unroll
      for (int t = 0; t < 2; ++t) {
        int n = t*16 + c16;
        short8 bf = *(const short8*)&w1T[n*128 + ((kc*32 + g*8) ^ ((n&7)<<3))];
        ha[t] = __builtin_amdgcn_mfma_f32_16x16x32_bf16(h1f[kc], bf, ha[t], 0, 0, 0);
      }

    // h2 = relu(ha + qa - ka + bias1) -> bf16 -> per-wave LDS
#pragma unroll
    for (int t = 0; t < 2; ++t)
#pragma unroll
      for (int r = 0; r < 4; ++r) {
        float v = ha[t][r] + qa_v[t] - ka_v[t][r] + bias1s[t*16 + c16];
        int row = g*4 + r, col = t*16 + c16;
        h2t[w][row*32 + (col ^ ((row&3)<<3))] = f2bf(fmaxf(v, 0.f));
      }
    WAVE_LDS_FENCE();

    short8 h2f = *(const short8*)&h2t[w][c16*32 + ((g*8) ^ ((c16&3)<<3))];

    // per-nt: logits (B from L1-resident aw2T), softmax, V, output
#pragma unroll 1
    for (int nt = 0; nt < 8; ++nt) {
      float ab = ab2s[nt*16 + c16];
      f32x4 cini = {ab, ab, ab, ab};
      short8 baw = *(const short8*)&aw2T[(nt*16 + c16)*32 + ((g*8) ^ (((nt*16 + c16)&3)<<3))];
      f32x4 lg = __builtin_amdgcn_mfma_f32_16x16x32_bf16(h2f, baw, cini, 0, 0, 0);

      float m = fmaxf(fmaxf(lg[0], lg[1]), fmaxf(lg[2], lg[3]));
      m = fmaxf(m, __shfl_xor(m, 16));
      m = fmaxf(m, __shfl_xor(m, 32));
      float e0 = __expf(lg[0]-m), e1 = __expf(lg[1]-m),
            e2 = __expf(lg[2]-m), e3 = __expf(lg[3]-m);
      float s = e0+e1+e2+e3;
      s += __shfl_xor(s, 16);
      s += __shfl_xor(s, 32);
      float inv = 1.0f / s;
      float pb = pb2s[nt*16 + c16];
      float v0 = vws[(size_t)(bofs + idr[0])*DIM + nt*16 + c16];
      float v1 = vws[(size_t)(bofs + idr[1])*DIM + nt*16 + c16];
      float v2 = vws[(size_t)(bofs + idr[2])*DIM + nt*16 + c16];
      float v3 = vws[(size_t)(bofs + idr[3])*DIM + nt*16 + c16];
      float acc = e0*(v0 + pe[nt][0] + pb)
                + e1*(v1 + pe[nt][1] + pb)
                + e2*(v2 + pe[nt][2] + pb)
                + e3*(v3 + pe[nt][3] + pb);
      acc *= inv;
      acc += __shfl_xor(acc, 16);
      acc += __shfl_xor(acc, 32);
      if (lane < 16) out[q*DIM + nt*16 + lane] = acc;
    }
  }
}

// ---------------- launch ----------------
extern "C" void kernel_launch(void* const* d_in, const int* in_sizes, int n_in,
                              void* d_out, int out_size, void* d_ws, size_t ws_size,
                              hipStream_t stream) {
  const float* x   = (const float*)d_in[0];
  const float* pos = (const float*)d_in[1];
  const float* pw1 = (const float*)d_in[2];
  const float* pb1 = (const float*)d_in[3];
  const float* pw2 = (const float*)d_in[4];
  const float* pb2 = (const float*)d_in[5];
  const float* qw  = (const float*)d_in[6];
  const float* qb  = (const float*)d_in[7];
  const float* kw  = (const float*)d_in[8];
  const float* kb  = (const float*)d_in[9];
  const float* vw  = (const float*)d_in[10];
  const float* vb  = (const float*)d_in[11];
  const float* aw1 = (const float*)d_in[12];
  const float* ab1 = (const float*)d_in[13];
  const float* aw2 = (const float*)d_in[14];
  const float* ab2 = (const float*)d_in[15];
  float* out = (float*)d_out;

  char* ws = (char*)d_ws;
  float4* pos4   = (float4*)(ws);                       // 256 KB
  int*    knnIdx = (int*)(ws + (1u<<20));               // 1 MB
  u32*    part   = (u32*)(ws + (2u<<20));               // 16 MB (dead after refine)
  float*  vws    = (float*)(ws + (2u<<20));             // 8 MB (reuse)
  float*  qa     = (float*)(ws + (11u<<20));            // 2 MB
  float*  ka     = (float*)(ws + (13u<<20));            // 2 MB
  char*   wsw    = ws + (19u<<20);                      // weights region
  u16*    pw2T  = (u16*)(wsw);                          // 32 KB
  u16*    w1T   = (u16*)(wsw + 32768);                  // 8 KB
  u16*    aw2T  = (u16*)(wsw + 40960);                  // 8 KB
  u16*    vwT   = (u16*)(wsw + 49152);                  // 32 KB
  u16*    Wq2T  = (u16*)(wsw + 81920);                  // 8 KB
  u16*    Wk2T  = (u16*)(wsw + 90112);                  // 8 KB
  float4* pw1q  = (float4*)(wsw + 98304);               // 2 KB
  float*  bias1 = (float*)(wsw + 100352);               // 128 B

  prep_all<<<221, 256, 0, stream>>>(pos, pw1, pb1, pw2, pb2, qw, qb, kw, kb, vw,
                                    aw1, ab1, aw2,
                                    pos4, pw2T, aw2T, vwT, w1T, Wq2T, Wk2T, pw1q, bias1);
  knn_scan<<<(NROWS/64)*NCHUNK/4, 256, 0, stream>>>(pos4, part);
  knn_refine<<<NROWS/16, 256, 0, stream>>>(pos4, part, knnIdx);
  proj_mfma<<<NROWS/64, 256, 0, stream>>>(x, vwT, Wq2T, Wk2T, vb, vws, qa, ka);
  attn_mfma<<<NROWS/16, 256, 0, stream>>>(pos4, knnIdx, vws, qa, ka,
                                          pw2T, w1T, aw2T, pw1q, bias1, pb2, ab2, out);
}

// Round 13
// 232.925 us; speedup vs baseline: 1.1441x; 1.0289x over previous
//
#include <hip/hip_runtime.h>
#include <hip/hip_bf16.h>
#include <stdint.h>

#define BATCH 4
#define NPTS  4096
#define DIM   128
#define KNN   16
#define NROWS (BATCH*NPTS)   // 16384
#define NCHUNK 16
#define CHUNK  (NPTS/NCHUNK) // 256

typedef unsigned long long u64;
typedef unsigned int u32;
typedef unsigned short u16;
typedef __attribute__((ext_vector_type(8))) short short8;
typedef __attribute__((ext_vector_type(4))) float f32x4;

__device__ __forceinline__ u16 f2bf(float f) {
  u32 u = __float_as_uint(f);
  u += 0x7FFFu + ((u >> 16) & 1);   // RNE
  return (u16)(u >> 16);
}

// wave-internal LDS fence (cross-lane visibility of same-wave DS stores)
#define WAVE_LDS_FENCE() asm volatile("s_waitcnt lgkmcnt(0)" ::: "memory")

// ---------------- ONE merged prep kernel ----------------
__global__ __launch_bounds__(256) void prep_all(
    const float* __restrict__ pos,
    const float* __restrict__ pw1, const float* __restrict__ pb1,
    const float* __restrict__ pw2, const float* __restrict__ pb2,
    const float* __restrict__ qw, const float* __restrict__ qb,
    const float* __restrict__ kw, const float* __restrict__ kb,
    const float* __restrict__ vw,
    const float* __restrict__ aw1, const float* __restrict__ ab1,
    const float* __restrict__ aw2,
    float4* __restrict__ pos4, u16* __restrict__ pw2T, u16* __restrict__ aw2T,
    u16* __restrict__ vwT, u16* __restrict__ w1T,
    u16* __restrict__ Wq2T, u16* __restrict__ Wk2T,
    float4* __restrict__ pw1q, float* __restrict__ bias1) {
  const int bid = blockIdx.x, tid = threadIdx.x;
  if (bid < 64) {
    int e = bid*256 + tid, k = e >> 7, n = e & 127;
    pw2T[n*128 + (k ^ ((n&7)<<3))] = f2bf(pw2[k*128 + n]);
  } else if (bid < 80) {
    int e = (bid-64)*256 + tid, k = e >> 7, n = e & 127;
    aw2T[n*32 + (k ^ ((n&3)<<3))] = f2bf(aw2[k*128 + n]);
  } else if (bid < 144) {
    int e = (bid-80)*256 + tid, k = e >> 7, n = e & 127;
    vwT[n*128 + (k ^ ((n&7)<<3))] = f2bf(vw[k*128 + n]);
  } else if (bid == 144) {
    if (tid < 128) {
      int c = tid;
      pw1q[c ^ ((c & 0x18) >> 2)] = make_float4(pw1[c], pw1[128+c], pw1[256+c], pb1[c]);
    } else if (tid < 160) {
      int j = tid - 128;
      float s = ab1[j];
      for (int c = 0; c < 128; ++c) s += (qb[c]-kb[c]+pb2[c]) * aw1[c*32+j];
      bias1[j] = s;
    }
  } else if (bid < 157) {
    int p = (bid-145) >> 2, qtr = (bid-145) & 3;
    const float* A = p == 0 ? pw2 : (p == 1 ? qw : kw);
    int j = tid & 31, r0 = qtr*32 + (tid >> 5)*4;
    float acc[4] = {0.f,0.f,0.f,0.f};
    for (int c = 0; c < 128; ++c) {
      float av = aw1[c*32 + j];
#pragma unroll
      for (int rr = 0; rr < 4; ++rr) acc[rr] = fmaf(A[(r0+rr)*128 + c], av, acc[rr]);
    }
#pragma unroll
    for (int rr = 0; rr < 4; ++rr) {
      int h = r0 + rr;
      u16 v = f2bf(acc[rr]);
      if (p == 0)      w1T [j*128 + (h ^ ((j&7)<<3))] = v;
      else if (p == 1) Wq2T[j*128 + (h ^ ((j&7)<<3))] = v;
      else             Wk2T[j*128 + (h ^ ((j&7)<<3))] = v;
    }
  } else {
    int i = (bid-157)*256 + tid;
    if (i < NROWS) pos4[i] = make_float4(pos[3*i], pos[3*i+1], pos[3*i+2], 0.f);
  }
}

// ---------------- branchless sorting primitives ----------------
template <typename T>
__device__ __forceinline__ void cex(T& a, T& b) {
  T mn = a < b ? a : b;
  T mx = a < b ? b : a;
  a = mn; b = mx;
}
template <typename T>
__device__ __forceinline__ void sort16(T x[16]) {
#pragma unroll
  for (int k = 2; k <= 16; k <<= 1)
#pragma unroll
    for (int j = k >> 1; j > 0; j >>= 1)
#pragma unroll
      for (int i = 0; i < 16; ++i) {
        int l = i ^ j;
        if (l > i) { if ((i & k) == 0) cex(x[i], x[l]); else cex(x[l], x[i]); }
      }
}
template <typename T>
__device__ __forceinline__ void merge16(T A[16], const T B[16]) {
#pragma unroll
  for (int i = 0; i < 16; ++i) { T b = B[15 - i]; A[i] = A[i] < b ? A[i] : b; }
#pragma unroll
  for (int j = 8; j > 0; j >>= 1)
#pragma unroll
    for (int i = 0; i < 16; ++i) { int l = i ^ j; if (l > i) cex(A[i], A[l]); }
}
__device__ __forceinline__ void bmerge32(u32 x[32]) {
#pragma unroll
  for (int j = 16; j > 0; j >>= 1)
#pragma unroll
    for (int i = 0; i < 32; ++i) { int l = i ^ j; if (l > i) cex(x[i], x[l]); }
}

// ---------------- fused kNN: scan (16 waves = 16 chunks) + merge tree + fp64 re-rank ----------------
// block = 1024 thr handles one 64-query group end-to-end; no global intermediate.
__global__ __launch_bounds__(1024) void knn_all(const float4* __restrict__ pos4,
                                                int* __restrict__ knnIdx) {
  __shared__ __align__(16) u32 lists[64][273];  // 69.9 KB: 16 sorted chunk-lists per query
  __shared__ __align__(16) u32 Bu[64][263];     // 67.3 KB: merge scratch; aliased as staging
  __shared__ u64 rk[64][35];                    // 17.9 KB: fp64 re-rank keys
  // total 151.5 KB -> 1 block/CU (16 waves)

  const int tid  = threadIdx.x;
  const int lane = tid & 63;      // scan phase: query within group
  const int w    = tid >> 6;      // scan phase: wave = chunk
  const int qbase = blockIdx.x * 64;
  const int b     = qbase >> 12;
  const int cbase = w * CHUNK;

  // Phase 0: wave w stages chunk w into Bu-alias (wave-local -> lgkmcnt fence only)
  {
    float4* cs = (float4*)&Bu[0][0];
    const float4* cand = pos4 + b*NPTS + cbase;
#pragma unroll
    for (int i = 0; i < CHUNK/64; ++i) cs[w*CHUNK + lane + 64*i] = cand[lane + 64*i];
  }
  WAVE_LDS_FENCE();

  // Phase 1: per-(query, chunk) top-16 on fp32 keys (identical to proven knn_scan)
  {
    const float4* cs = (const float4*)&Bu[0][0];
    float4 qp = pos4[qbase + lane];
    const float qx = qp.x, qy = qp.y, qz = qp.z;

    u32 best[16];
#pragma unroll
    for (int i = 0; i < 16; ++i) best[i] = ~0u;

#pragma unroll 1
    for (int m = 0; m < CHUNK/16; ++m) {
      u32 batch[16];
#pragma unroll
      for (int e = 0; e < 16; ++e) {
        float4 p = cs[w*CHUNK + m*16 + e];
        float dx = qx - p.x, dy = qy - p.y, dz = qz - p.z;
        float d  = fmaf(dx, dx, fmaf(dy, dy, dz*dz));
        batch[e] = (__float_as_uint(d) & 0xFFFFF000u) | (u32)(cbase + m*16 + e);
      }
      u32 bmin = batch[0];
#pragma unroll
      for (int e = 1; e < 16; ++e) bmin = batch[e] < bmin ? batch[e] : bmin;
      if (__any(bmin < best[15])) {
        sort16(batch);
        merge16(best, batch);
      }
    }
#pragma unroll
    for (int s = 0; s < 16; ++s) lists[lane][w*17 + s] = best[s];
  }
  __syncthreads();

  // merge-tree phases: qi = query (0..63), c = 0..15 (16 threads/query)
  const int qi = tid >> 4, c = tid & 15;

  if (c < 8) {   // L1: merge sorted-16 pairs -> sorted-32
    u32 x[32];
#pragma unroll
    for (int s = 0; s < 16; ++s) x[s]      = lists[qi][(2*c)*17 + s];
#pragma unroll
    for (int s = 0; s < 16; ++s) x[16 + s] = lists[qi][(2*c+1)*17 + 15 - s];
    bmerge32(x);
#pragma unroll
    for (int s = 0; s < 32; ++s) Bu[qi][c*33 + s] = x[s];
  }
  __syncthreads();

  if (c < 4) {   // L2: keep-32 (lists region now dead -> reuse)
    u32 x[32];
#pragma unroll
    for (int s = 0; s < 32; ++s) {
      u32 a = Bu[qi][(2*c)*33 + s], bb = Bu[qi][(2*c+1)*33 + 31 - s];
      x[s] = a < bb ? a : bb;
    }
    bmerge32(x);
#pragma unroll
    for (int s = 0; s < 32; ++s) lists[qi][c*33 + s] = x[s];
  }
  __syncthreads();

  if (c < 2) {   // L3
    u32 x[32];
#pragma unroll
    for (int s = 0; s < 32; ++s) {
      u32 a = lists[qi][(2*c)*33 + s], bb = lists[qi][(2*c+1)*33 + 31 - s];
      x[s] = a < bb ? a : bb;
    }
    bmerge32(x);
#pragma unroll
    for (int s = 0; s < 32; ++s) Bu[qi][c*33 + s] = x[s];
  }
  __syncthreads();

  if (c == 0) {  // L4 -> pool32 at Bu[qi][132..163]
    u32 x[32];
#pragma unroll
    for (int s = 0; s < 32; ++s) {
      u32 a = Bu[qi][s], bb = Bu[qi][33 + 31 - s];
      x[s] = a < bb ? a : bb;
    }
    bmerge32(x);
#pragma unroll
    for (int s = 0; s < 32; ++s) Bu[qi][132 + s] = x[s];
  }
  __syncthreads();

  if (c < 2) {   // fp64 re-rank of the 32-pool (proven key formula, bit-identical)
    float4 qp = pos4[qbase + qi];
    const double qx = qp.x, qy = qp.y, qz = qp.z;
    u64 key[16];
#pragma unroll
    for (int s = 0; s < 16; ++s) {
      int idx = (int)(Bu[qi][132 + c*16 + s] & 0xFFFu);
      float4 p = pos4[(b<<12) + idx];
      double dx = qx - (double)p.x;
      double dy = qy - (double)p.y;
      double dz = qz - (double)p.z;
      double d  = fma(dx, dx, fma(dy, dy, dz*dz));
      key[s] = (((u64)__double_as_longlong(d)) & ~0xFFFull) | (u64)idx;
    }
    sort16(key);
#pragma unroll
    for (int s = 0; s < 16; ++s) rk[qi][c*17 + s] = key[s];
  }
  __syncthreads();

  if (c == 0) {
    u64 best[16], nb[16];
#pragma unroll
    for (int s = 0; s < 16; ++s) { best[s] = rk[qi][s]; nb[s] = rk[qi][17 + s]; }
    merge16(best, nb);
    const int outq = (qbase + qi) * KNN;
#pragma unroll
    for (int s = 0; s < 16; ++s) knnIdx[outq + s] = (int)(best[s] & 0xFFFull);
  }
}

// ---------------- proj via MFMA: V + qa + ka (bf16 in, fp32 out) ----------------
__global__ __launch_bounds__(256) void proj_mfma(
    const float* __restrict__ x, const u16* __restrict__ vwT,
    const u16* __restrict__ Wq2T, const u16* __restrict__ Wk2T,
    const float* __restrict__ vb,
    float* __restrict__ vo, float* __restrict__ qa, float* __restrict__ ka) {
  const int lane = threadIdx.x & 63, w = threadIdx.x >> 6;
  const int c16 = lane & 15, g = lane >> 4;
  const int row0 = (blockIdx.x*4 + w)*16;

  const float* xrow = x + (size_t)(row0 + c16)*DIM;
  short8 af[4];
#pragma unroll
  for (int kc = 0; kc < 4; ++kc) {
    float4 a0 = *(const float4*)&xrow[kc*32 + g*8];
    float4 a1 = *(const float4*)&xrow[kc*32 + g*8 + 4];
    short8 s;
    s[0]=(short)f2bf(a0.x); s[1]=(short)f2bf(a0.y); s[2]=(short)f2bf(a0.z); s[3]=(short)f2bf(a0.w);
    s[4]=(short)f2bf(a1.x); s[5]=(short)f2bf(a1.y); s[6]=(short)f2bf(a1.z); s[7]=(short)f2bf(a1.w);
    af[kc] = s;
  }

#pragma unroll
  for (int nt = 0; nt < 8; ++nt) {
    int n = nt*16 + c16;
    float bb = vb[n];
    f32x4 acc = {bb, bb, bb, bb};
#pragma unroll
    for (int kc = 0; kc < 4; ++kc) {
      short8 bf = *(const short8*)&vwT[n*128 + ((kc*32 + g*8) ^ ((n&7)<<3))];
      acc = __builtin_amdgcn_mfma_f32_16x16x32_bf16(af[kc], bf, acc, 0, 0, 0);
    }
#pragma unroll
    for (int r = 0; r < 4; ++r)
      vo[(size_t)(row0 + g*4 + r)*DIM + n] = acc[r];
  }

#pragma unroll
  for (int t = 0; t < 2; ++t) {
    int n = t*16 + c16;
    f32x4 aq = {0.f,0.f,0.f,0.f}, ak = {0.f,0.f,0.f,0.f};
#pragma unroll
    for (int kc = 0; kc < 4; ++kc) {
      short8 bq = *(const short8*)&Wq2T[n*128 + ((kc*32 + g*8) ^ ((n&7)<<3))];
      short8 bk = *(const short8*)&Wk2T[n*128 + ((kc*32 + g*8) ^ ((n&7)<<3))];
      aq = __builtin_amdgcn_mfma_f32_16x16x32_bf16(af[kc], bq, aq, 0, 0, 0);
      ak = __builtin_amdgcn_mfma_f32_16x16x32_bf16(af[kc], bk, ak, 0, 0, 0);
    }
#pragma unroll
    for (int r = 0; r < 4; ++r) {
      qa[(row0 + g*4 + r)*32 + n] = aq[r];
      ka[(row0 + g*4 + r)*32 + n] = ak[r];
    }
  }
}

// ---------------- fused MFMA attention (unchanged from round 12) ----------------
__global__ __launch_bounds__(256, 4) void attn_mfma(
    const float4* __restrict__ pos4, const int* __restrict__ knnIdx,
    const float* __restrict__ vws, const float* __restrict__ qa, const float* __restrict__ ka,
    const u16* __restrict__ pw2T, const u16* __restrict__ w1T, const u16* __restrict__ aw2T,
    const float4* __restrict__ pw1q, const float* __restrict__ bias1,
    const float* __restrict__ pb2, const float* __restrict__ ab2,
    float* __restrict__ out) {
  __shared__ __align__(16) u16 pw2s[16384];   // 32 KB
  __shared__ __align__(16) float4 pw1s[128];  // 2 KB
  __shared__ float bias1s[32], pb2s[128], ab2s[128];
  __shared__ __align__(16) u16 h2t[4][512];   // per-wave, 4 KB

  const int tid = threadIdx.x;
  {
    const uint4* s1 = (const uint4*)pw2T; uint4* d1 = (uint4*)pw2s;
#pragma unroll
    for (int i = 0; i < 8; ++i) d1[tid + 256*i] = s1[tid + 256*i];
    if (tid < 128) { pw1s[tid] = pw1q[tid]; pb2s[tid] = pb2[tid]; ab2s[tid] = ab2[tid]; }
    else if (tid < 160) bias1s[tid-128] = bias1[tid-128];
  }
  __syncthreads();   // only block barrier

  const int lane = tid & 63, w = tid >> 6;
  const int c16 = lane & 15, g = lane >> 4;

  const int swz = (blockIdx.x & 7) * 128 + (blockIdx.x >> 3);
  const int qblock = swz * 16;
  const int qbase  = qblock + w * 4;
  const int bofs   = (qblock >> 12) << 12;

  int id_own = knnIdx[qbase*KNN + lane];
  float4 pq = pos4[qbase + g];
  float4 pn = pos4[bofs + id_own];
  float rox = pq.x - pn.x, roy = pq.y - pn.y, roz = pq.z - pn.z;

#pragma unroll 1
  for (int j = 0; j < 4; ++j) {
    const int q = qbase + j;
    float relx = __shfl(rox, j*16 + c16);
    float rely = __shfl(roy, j*16 + c16);
    float relz = __shfl(roz, j*16 + c16);
    int idr[4];
#pragma unroll
    for (int r = 0; r < 4; ++r) idr[r] = __shfl(id_own, j*16 + g*4 + r);

    float qa_v[2], ka_v[2][4];
#pragma unroll
    for (int t = 0; t < 2; ++t) qa_v[t] = qa[q*32 + t*16 + c16];
#pragma unroll
    for (int r = 0; r < 4; ++r)
#pragma unroll
      for (int t = 0; t < 2; ++t) ka_v[t][r] = ka[(bofs + idr[r])*32 + t*16 + c16];

    short8 h1f[4];
#pragma unroll
    for (int kc = 0; kc < 4; ++kc) {
      short8 s;
#pragma unroll
      for (int jj = 0; jj < 8; ++jj) {
        int c = kc*32 + g*8 + jj;
        float4 wv = pw1s[c ^ ((c & 0x18) >> 2)];
        float h = fmaf(relx, wv.x, fmaf(rely, wv.y, fmaf(relz, wv.z, wv.w)));
        s[jj] = (short)f2bf(fmaxf(h, 0.f));
      }
      h1f[kc] = s;
    }

    f32x4 pe[8];
#pragma unroll
    for (int nt = 0; nt < 8; ++nt) { f32x4 z = {0.f,0.f,0.f,0.f}; pe[nt] = z; }
#pragma unroll
    for (int kc = 0; kc < 4; ++kc)
#pragma unroll
      for (int nt = 0; nt < 8; ++nt) {
        int n = nt*16 + c16;
        short8 bf = *(const short8*)&pw2s[n*128 + ((kc*32 + g*8) ^ ((n&7)<<3))];
        pe[nt] = __builtin_amdgcn_mfma_f32_16x16x32_bf16(h1f[kc], bf, pe[nt], 0, 0, 0);
      }

    f32x4 ha[2];
#pragma unroll
    for (int t = 0; t < 2; ++t) { f32x4 z = {0.f,0.f,0.f,0.f}; ha[t] = z; }
#pragma unroll
    for (int kc = 0; kc < 4; ++kc)
#pragma unroll
      for (int t = 0; t < 2; ++t) {
        int n = t*16 + c16;
        short8 bf = *(const short8*)&w1T[n*128 + ((kc*32 + g*8) ^ ((n&7)<<3))];
        ha[t] = __builtin_amdgcn_mfma_f32_16x16x32_bf16(h1f[kc], bf, ha[t], 0, 0, 0);
      }

#pragma unroll
    for (int t = 0; t < 2; ++t)
#pragma unroll
      for (int r = 0; r < 4; ++r) {
        float v = ha[t][r] + qa_v[t] - ka_v[t][r] + bias1s[t*16 + c16];
        int row = g*4 + r, col = t*16 + c16;
        h2t[w][row*32 + (col ^ ((row&3)<<3))] = f2bf(fmaxf(v, 0.f));
      }
    WAVE_LDS_FENCE();

    short8 h2f = *(const short8*)&h2t[w][c16*32 + ((g*8) ^ ((c16&3)<<3))];

#pragma unroll 1
    for (int nt = 0; nt < 8; ++nt) {
      float ab = ab2s[nt*16 + c16];
      f32x4 cini = {ab, ab, ab, ab};
      short8 baw = *(const short8*)&aw2T[(nt*16 + c16)*32 + ((g*8) ^ (((nt*16 + c16)&3)<<3))];
      f32x4 lg = __builtin_amdgcn_mfma_f32_16x16x32_bf16(h2f, baw, cini, 0, 0, 0);

      float m = fmaxf(fmaxf(lg[0], lg[1]), fmaxf(lg[2], lg[3]));
      m = fmaxf(m, __shfl_xor(m, 16));
      m = fmaxf(m, __shfl_xor(m, 32));
      float e0 = __expf(lg[0]-m), e1 = __expf(lg[1]-m),
            e2 = __expf(lg[2]-m), e3 = __expf(lg[3]-m);
      float s = e0+e1+e2+e3;
      s += __shfl_xor(s, 16);
      s += __shfl_xor(s, 32);
      float inv = 1.0f / s;
      float pb = pb2s[nt*16 + c16];
      float v0 = vws[(size_t)(bofs + idr[0])*DIM + nt*16 + c16];
      float v1 = vws[(size_t)(bofs + idr[1])*DIM + nt*16 + c16];
      float v2 = vws[(size_t)(bofs + idr[2])*DIM + nt*16 + c16];
      float v3 = vws[(size_t)(bofs + idr[3])*DIM + nt*16 + c16];
      float acc = e0*(v0 + pe[nt][0] + pb)
                + e1*(v1 + pe[nt][1] + pb)
                + e2*(v2 + pe[nt][2] + pb)
                + e3*(v3 + pe[nt][3] + pb);
      acc *= inv;
      acc += __shfl_xor(acc, 16);
      acc += __shfl_xor(acc, 32);
      if (lane < 16) out[q*DIM + nt*16 + lane] = acc;
    }
  }
}

// ---------------- launch ----------------
extern "C" void kernel_launch(void* const* d_in, const int* in_sizes, int n_in,
                              void* d_out, int out_size, void* d_ws, size_t ws_size,
                              hipStream_t stream) {
  const float* x   = (const float*)d_in[0];
  const float* pos = (const float*)d_in[1];
  const float* pw1 = (const float*)d_in[2];
  const float* pb1 = (const float*)d_in[3];
  const float* pw2 = (const float*)d_in[4];
  const float* pb2 = (const float*)d_in[5];
  const float* qw  = (const float*)d_in[6];
  const float* qb  = (const float*)d_in[7];
  const float* kw  = (const float*)d_in[8];
  const float* kb  = (const float*)d_in[9];
  const float* vw  = (const float*)d_in[10];
  const float* vb  = (const float*)d_in[11];
  const float* aw1 = (const float*)d_in[12];
  const float* ab1 = (const float*)d_in[13];
  const float* aw2 = (const float*)d_in[14];
  const float* ab2 = (const float*)d_in[15];
  float* out = (float*)d_out;

  char* ws = (char*)d_ws;
  float4* pos4   = (float4*)(ws);                       // 256 KB
  int*    knnIdx = (int*)(ws + (1u<<20));               // 1 MB
  float*  vws    = (float*)(ws + (2u<<20));             // 8 MB
  float*  qa     = (float*)(ws + (11u<<20));            // 2 MB
  float*  ka     = (float*)(ws + (13u<<20));            // 2 MB
  char*   wsw    = ws + (19u<<20);                      // weights region
  u16*    pw2T  = (u16*)(wsw);                          // 32 KB
  u16*    w1T   = (u16*)(wsw + 32768);                  // 8 KB
  u16*    aw2T  = (u16*)(wsw + 40960);                  // 8 KB
  u16*    vwT   = (u16*)(wsw + 49152);                  // 32 KB
  u16*    Wq2T  = (u16*)(wsw + 81920);                  // 8 KB
  u16*    Wk2T  = (u16*)(wsw + 90112);                  // 8 KB
  float4* pw1q  = (float4*)(wsw + 98304);               // 2 KB
  float*  bias1 = (float*)(wsw + 100352);               // 128 B

  prep_all<<<221, 256, 0, stream>>>(pos, pw1, pb1, pw2, pb2, qw, qb, kw, kb, vw,
                                    aw1, ab1, aw2,
                                    pos4, pw2T, aw2T, vwT, w1T, Wq2T, Wk2T, pw1q, bias1);
  knn_all<<<NROWS/64, 1024, 0, stream>>>(pos4, knnIdx);
  proj_mfma<<<NROWS/64, 256, 0, stream>>>(x, vwT, Wq2T, Wk2T, vb, vws, qa, ka);
  attn_mfma<<<NROWS/16, 256, 0, stream>>>(pos4, knnIdx, vws, qa, ka,
                                          pw2T, w1T, aw2T, pw1q, bias1, pb2, ab2, out);
}